// Round 9
// baseline (1044.545 us; speedup 1.0000x reference)
//
#include <hip/hip_runtime.h>
#include <cstdint>
#include <cstddef>

#define HIDC 128
#define NHEAD 8
#define NLAY 3
#define NGRAPH 64
#define NCLS 3
#define MAXI 6   // fast path deg <= 48

typedef __attribute__((ext_vector_type(8))) short short8;
typedef __attribute__((ext_vector_type(4))) float floatx4;

__device__ inline short f2bf(float x) {
  unsigned u = __float_as_uint(x);
  unsigned r = (u + 0x7fff + ((u >> 16) & 1)) >> 16;   // RNE
  return (short)r;
}
__device__ inline float bf2f(unsigned short u) {
  return __uint_as_float(((unsigned)u) << 16);
}

// ---------------------------------------------------------------------------
// Weight prep
// ---------------------------------------------------------------------------
__global__ void convt_kernel(const float* __restrict__ W, short* __restrict__ Wt,
                             int K, int Nc)
{
  int i = blockIdx.x * 256 + threadIdx.x;
  if (i >= K * Nc) return;
  int k = i / Nc, n = i - k * Nc;
  Wt[(size_t)n * K + k] = f2bf(W[i]);
}

// Wp[l][c][h*128+k] = gat_W[l][k][h*128+c] / 8   (head-mean folded in)
__global__ void rearr_kernel(const float* __restrict__ gat_W, short* __restrict__ Wp)
{
  int i = blockIdx.x * 256 + threadIdx.x;
  if (i >= NLAY * 131072) return;
  int l = i >> 17, rem = i & 131071;
  int k = rem >> 10, hc = rem & 1023;
  int hh = hc >> 7, cc = hc & 127;
  Wp[(size_t)l * 131072 + (size_t)cc * 1024 + hh * 128 + k] = f2bf(gat_W[i] * 0.125f);
}

// waSD[l][k][j16]: j16<8 -> W_h a_src_h projection, j16>=8 -> a_dst
__global__ __launch_bounds__(256) void wa_kernel(
    const float* __restrict__ gat_W, const float* __restrict__ att_src,
    const float* __restrict__ att_dst, float* __restrict__ waSD)
{
  int l = blockIdx.x;
  int idx = blockIdx.y * 256 + threadIdx.x;
  int k = idx >> 4, j16 = idx & 15;
  int hh = j16 & 7;
  const float* a = ((j16 < 8) ? att_src : att_dst) + (size_t)l * 1024 + hh * 128;
  const float* w = gat_W + (size_t)l * 131072 + (size_t)k * 1024 + hh * 128;
  float s = 0.f;
  for (int cc = 0; cc < 128; ++cc) s += w[cc] * a[cc];
  waSD[(size_t)l * 2048 + idx] = s;
}

// Bt512[col][k] for fused GRU matmul over A=[h_bf16 | mem_bf16] (K=256)
__global__ void build_gru_B(const float* __restrict__ W_ih,
                            const float* __restrict__ W_hh,
                            short* __restrict__ Bt512)
{
  int i = blockIdx.x * 256 + threadIdx.x;
  if (i >= 512 * 256) return;
  int col = i >> 8, k = i & 255;
  float v;
  if (k < 128) {
    if (col < 384) v = W_ih[(size_t)col * 128 + k];
    else v = 0.f;
  } else {
    int k2 = k - 128;
    if (col < 256) v = W_hh[(size_t)col * 128 + k2];
    else if (col < 384) v = 0.f;
    else v = W_hh[(size_t)(col - 128) * 128 + k2];
  }
  Bt512[i] = f2bf(v);
}

// ---------------------------------------------------------------------------
// Encoder: C[M,Nc] = relu(A_fp32[M,128] @ B + bias), Bt[Nc][128] bf16.
// ---------------------------------------------------------------------------
__global__ __launch_bounds__(256) void mm_bf16(
    const float* __restrict__ A, const short* __restrict__ Bt,
    const float* __restrict__ bias, unsigned short* __restrict__ Cb2,
    int M, int Nc, int relu)
{
  __shared__ short Asl[64 * 136];
  const int tid = threadIdx.x;
  const int m0 = blockIdx.x * 64;
  const int n0 = blockIdx.y * 64;

  const float4* A4 = (const float4*)A;
#pragma unroll
  for (int it = 0; it < 8; ++it) {
    int idx = tid + it * 256;
    int r = idx >> 5, k4 = idx & 31;
    int row = m0 + r; if (row >= M) row = M - 1;
    float4 a = A4[(size_t)row * 32 + k4];
    ushort4 p;
    p.x = (unsigned short)f2bf(a.x); p.y = (unsigned short)f2bf(a.y);
    p.z = (unsigned short)f2bf(a.z); p.w = (unsigned short)f2bf(a.w);
    *(ushort4*)&Asl[r * 136 + k4 * 4] = p;
  }
  __syncthreads();

  const int wid = tid >> 6, lane = tid & 63;
  const int l15 = lane & 15, quad = lane >> 4;
  const int wm = wid & 1, wn = wid >> 1;
  const int mb = wm * 32;
  const int nb = n0 + wn * 32;

  floatx4 acc00 = {0.f, 0.f, 0.f, 0.f};
  floatx4 acc01 = acc00, acc10 = acc00, acc11 = acc00;

#pragma unroll
  for (int kk = 0; kk < 4; ++kk) {
    int k = kk * 32 + quad * 8;
    short8 a0 = *(const short8*)&Asl[(mb + l15) * 136 + k];
    short8 a1 = *(const short8*)&Asl[(mb + 16 + l15) * 136 + k];
    short8 b0 = *(const short8*)&Bt[(size_t)(nb + l15) * 128 + k];
    short8 b1 = *(const short8*)&Bt[(size_t)(nb + 16 + l15) * 128 + k];
    acc00 = __builtin_amdgcn_mfma_f32_16x16x32_bf16(a0, b0, acc00, 0, 0, 0);
    acc01 = __builtin_amdgcn_mfma_f32_16x16x32_bf16(a0, b1, acc01, 0, 0, 0);
    acc10 = __builtin_amdgcn_mfma_f32_16x16x32_bf16(a1, b0, acc10, 0, 0, 0);
    acc11 = __builtin_amdgcn_mfma_f32_16x16x32_bf16(a1, b1, acc11, 0, 0, 0);
  }

#pragma unroll
  for (int mt = 0; mt < 2; ++mt) {
#pragma unroll
    for (int nt = 0; nt < 2; ++nt) {
      floatx4 acc = (mt == 0) ? (nt == 0 ? acc00 : acc01)
                              : (nt == 0 ? acc10 : acc11);
      int colg = nb + nt * 16 + l15;
      float bv = bias ? bias[colg] : 0.f;
#pragma unroll
      for (int r = 0; r < 4; ++r) {
        int rowg = m0 + mb + mt * 16 + quad * 4 + r;
        if (rowg < M && colg < Nc) {
          float v = acc[r] + bv;
          if (relu) v = fmaxf(v, 0.f);
          Cb2[(size_t)rowg * Nc + colg] = (unsigned short)f2bf(v);
        }
      }
    }
  }
}

// ---------------------------------------------------------------------------
// mm_direct: C[M,128] = act(A_bf16[M,K] @ B + bias), Bt[128][K] bf16.
// NO LDS, NO barriers: A-fragments NT-loaded directly (wave = 16 rows x 64B).
// 64 rows x 128 cols per block; wave: wm = row-tile(32), wn = col-half(64).
// ---------------------------------------------------------------------------
__global__ __launch_bounds__(256, 8) void mm_direct(
    const unsigned short* __restrict__ A, const short* __restrict__ Bt,
    const float* __restrict__ bias, unsigned short* __restrict__ C,
    int M, int K, int relu)
{
  const int tid = threadIdx.x;
  const int wid = tid >> 6, lane = tid & 63;
  const int l15 = lane & 15, quad = lane >> 4;
  const int wm = wid & 1, wn = wid >> 1;
  const int m0 = blockIdx.x * 64 + wm * 32;
  const int nb = wn * 64;
  int r0 = m0 + l15;      if (r0 >= M) r0 = M - 1;
  int r1 = m0 + 16 + l15; if (r1 >= M) r1 = M - 1;
  const short8* A0 = (const short8*)(A + (size_t)r0 * K + quad * 8);
  const short8* A1 = (const short8*)(A + (size_t)r1 * K + quad * 8);

  floatx4 acc[2][4];
#pragma unroll
  for (int a = 0; a < 2; ++a)
#pragma unroll
    for (int g = 0; g < 4; ++g) acc[a][g] = (floatx4){0.f, 0.f, 0.f, 0.f};

  for (int kb = 0; kb < K; kb += 32) {
    short8 a0 = __builtin_nontemporal_load(A0); A0 += 4;   // 4*short8 = 32 shorts
    short8 a1 = __builtin_nontemporal_load(A1); A1 += 4;
#pragma unroll
    for (int g = 0; g < 4; ++g) {
      int col = nb + g * 16 + l15;
      short8 b = *(const short8*)&Bt[(size_t)col * K + kb + quad * 8];
      acc[0][g] = __builtin_amdgcn_mfma_f32_16x16x32_bf16(a0, b, acc[0][g], 0, 0, 0);
      acc[1][g] = __builtin_amdgcn_mfma_f32_16x16x32_bf16(a1, b, acc[1][g], 0, 0, 0);
    }
  }

#pragma unroll
  for (int mt = 0; mt < 2; ++mt) {
#pragma unroll
    for (int g = 0; g < 4; ++g) {
      int colg = nb + g * 16 + l15;
      float bv = bias[colg];
#pragma unroll
      for (int r = 0; r < 4; ++r) {
        int rowg = m0 + mt * 16 + quad * 4 + r;
        if (rowg < M) {
          float v = acc[mt][g][r] + bv;
          if (relu) v = fmaxf(v, 0.f);
          C[(size_t)rowg * 128 + colg] = (unsigned short)f2bf(v);
        }
      }
    }
  }
}

// ---------------------------------------------------------------------------
// gru_mm_direct: S[M,512] = [hb | mem->bf16] @ Bt512^T, K=256, no LDS.
// grid (ceil(M/64), 4); block covers 64 rows x 128 cols (n0 = by*128).
// ---------------------------------------------------------------------------
__global__ __launch_bounds__(256, 8) void gru_mm_direct(
    const unsigned short* __restrict__ hb, const float* __restrict__ mem,
    const short* __restrict__ Bt512, unsigned short* __restrict__ S, int M)
{
  const int tid = threadIdx.x;
  const int wid = tid >> 6, lane = tid & 63;
  const int l15 = lane & 15, quad = lane >> 4;
  const int wm = wid & 1, wn = wid >> 1;
  const int m0 = blockIdx.x * 64 + wm * 32;
  const int nb = blockIdx.y * 128 + wn * 64;
  int r0 = m0 + l15;      if (r0 >= M) r0 = M - 1;
  int r1 = m0 + 16 + l15; if (r1 >= M) r1 = M - 1;

  floatx4 acc[2][4];
#pragma unroll
  for (int a = 0; a < 2; ++a)
#pragma unroll
    for (int g = 0; g < 4; ++g) acc[a][g] = (floatx4){0.f, 0.f, 0.f, 0.f};

#pragma unroll
  for (int kb = 0; kb < 256; kb += 32) {
    short8 a0, a1;
    if (kb < 128) {
      a0 = *(const short8*)&hb[(size_t)r0 * 128 + kb + quad * 8];
      a1 = *(const short8*)&hb[(size_t)r1 * 128 + kb + quad * 8];
    } else {
      const float* p0 = mem + (size_t)r0 * 128 + (kb - 128) + quad * 8;
      const float* p1 = mem + (size_t)r1 * 128 + (kb - 128) + quad * 8;
      float4 x0 = *(const float4*)p0, y0 = *(const float4*)(p0 + 4);
      float4 x1 = *(const float4*)p1, y1 = *(const float4*)(p1 + 4);
      a0[0] = f2bf(x0.x); a0[1] = f2bf(x0.y); a0[2] = f2bf(x0.z); a0[3] = f2bf(x0.w);
      a0[4] = f2bf(y0.x); a0[5] = f2bf(y0.y); a0[6] = f2bf(y0.z); a0[7] = f2bf(y0.w);
      a1[0] = f2bf(x1.x); a1[1] = f2bf(x1.y); a1[2] = f2bf(x1.z); a1[3] = f2bf(x1.w);
      a1[4] = f2bf(y1.x); a1[5] = f2bf(y1.y); a1[6] = f2bf(y1.z); a1[7] = f2bf(y1.w);
    }
#pragma unroll
    for (int g = 0; g < 4; ++g) {
      int col = nb + g * 16 + l15;
      short8 b = *(const short8*)&Bt512[(size_t)col * 256 + kb + quad * 8];
      acc[0][g] = __builtin_amdgcn_mfma_f32_16x16x32_bf16(a0, b, acc[0][g], 0, 0, 0);
      acc[1][g] = __builtin_amdgcn_mfma_f32_16x16x32_bf16(a1, b, acc[1][g], 0, 0, 0);
    }
  }

#pragma unroll
  for (int mt = 0; mt < 2; ++mt) {
#pragma unroll
    for (int g = 0; g < 4; ++g) {
      int colg = nb + g * 16 + l15;
#pragma unroll
      for (int r = 0; r < 4; ++r) {
        int rowg = m0 + mt * 16 + quad * 4 + r;
        if (rowg < M) {
          unsigned short v = (unsigned short)f2bf(acc[mt][g][r]);
          __builtin_nontemporal_store(v, &S[(size_t)rowg * 512 + colg]);
        }
      }
    }
  }
}

// ---------------------------------------------------------------------------
// Fused GRU gates + global_mean_pool (run-length accumulate, atomic flush)
// ---------------------------------------------------------------------------
__global__ __launch_bounds__(128) void gru_gate_pool(
    const unsigned short* __restrict__ S, const float* __restrict__ mem,
    const float* __restrict__ bI, const float* __restrict__ bH,
    const int* __restrict__ batch, float* __restrict__ pooled_sums,
    float* __restrict__ cnt, int N)
{
  int n0 = blockIdx.x * 128;
  int c = threadIdx.x;
  if (n0 >= N) return;
  int end = n0 + 128; if (end > N) end = N;
  const float bIr = bI[c],       bHr = bH[c];
  const float bIz = bI[128 + c], bHz = bH[128 + c];
  const float bIn = bI[256 + c], bHn = bH[256 + c];
  int cur = batch[n0];
  float acc = 0.f, count = 0.f;
  for (int n = n0; n < end; ++n) {
    int b = batch[n];
    if (b != cur) {
      atomicAdd(&pooled_sums[(size_t)cur * HIDC + c], acc);
      if (c == 0) atomicAdd(&cnt[cur], count);
      acc = 0.f; count = 0.f; cur = b;
    }
    size_t base = (size_t)n * 512;
    float sr  = bf2f(__builtin_nontemporal_load(&S[base + c]))       + bIr + bHr;
    float sz  = bf2f(__builtin_nontemporal_load(&S[base + 128 + c])) + bIz + bHz;
    float gin = bf2f(__builtin_nontemporal_load(&S[base + 256 + c])) + bIn;
    float ghn = bf2f(__builtin_nontemporal_load(&S[base + 384 + c])) + bHn;
    float rg = 1.f / (1.f + __expf(-sr));
    float zg = 1.f / (1.f + __expf(-sz));
    float nc = tanhf(gin + rg * ghn);
    float hv = (1.f - zg) * nc + zg * mem[(size_t)n * 128 + c];
    acc += hv; count += 1.f;
  }
  atomicAdd(&pooled_sums[(size_t)cur * HIDC + c], acc);
  if (c == 0) atomicAdd(&cnt[cur], count);
}

// ---------------------------------------------------------------------------
// alphas from bf16 h: aS/aD[n][h] = h[n,:] . waSD[:,j16]
// ---------------------------------------------------------------------------
__global__ __launch_bounds__(256) void alpha2b_kernel(
    const unsigned short* __restrict__ hb, const float* __restrict__ waSD,
    float* __restrict__ aS, float* __restrict__ aD, int N)
{
  __shared__ float s_wa[2048];
  const int tid = threadIdx.x;
  for (int i = tid; i < 2048; i += 256) s_wa[i] = waSD[i];
  __syncthreads();
  int node = blockIdx.x * 16 + (tid >> 4);
  int j = tid & 15;
  if (node >= N) return;
  const short8* h8 = (const short8*)(hb + (size_t)node * 128);
  float s = 0.f;
#pragma unroll
  for (int k8 = 0; k8 < 16; ++k8) {
    short8 v = h8[k8];
#pragma unroll
    for (int t = 0; t < 8; ++t)
      s += bf2f((unsigned short)v[t]) * s_wa[(k8 * 8 + t) * 16 + j];
  }
  if (j < 8) aS[(size_t)node * 8 + j] = s;
  else       aD[(size_t)node * 8 + (j - 8)] = s;
}

// ---------------------------------------------------------------------------
// CSR build: histogram, 3-stage scan, scatter
// ---------------------------------------------------------------------------
__global__ void hist_kernel(const int* __restrict__ ei, int* __restrict__ deg, int E, int N)
{
  int i = blockIdx.x * 256 + threadIdx.x;
  if (i >= E + N) return;
  int dst = (i < E) ? ei[E + i] : (i - E);
  atomicAdd(&deg[dst], 1);
}

__global__ __launch_bounds__(1024) void scan1_kernel(
    const int* __restrict__ deg, int* __restrict__ rowptr,
    int* __restrict__ bsum, int N)
{
  __shared__ int sd[1024];
  int i = blockIdx.x * 1024 + threadIdx.x;
  int v = (i < N) ? deg[i] : 0;
  sd[threadIdx.x] = v;
  __syncthreads();
  for (int off = 1; off < 1024; off <<= 1) {
    int t = (threadIdx.x >= off) ? sd[threadIdx.x - off] : 0;
    __syncthreads();
    sd[threadIdx.x] += t;
    __syncthreads();
  }
  if (i < N) rowptr[i] = sd[threadIdx.x] - v;
  if (threadIdx.x == 1023) bsum[blockIdx.x] = sd[1023];
}

__global__ __launch_bounds__(64) void scan2_kernel(int* __restrict__ bsum, int nb)
{
  int lane = threadIdx.x;
  int v = (lane < nb) ? bsum[lane] : 0;
  int incl = v;
  for (int off = 1; off < 64; off <<= 1) {
    int t = __shfl_up(incl, off);
    if (lane >= off) incl += t;
  }
  if (lane < nb) bsum[lane] = incl - v;
}

__global__ void scan3_kernel(int* __restrict__ rowptr, const int* __restrict__ bsum,
                             int N, int EN)
{
  int i = blockIdx.x * 256 + threadIdx.x;
  if (i < N) rowptr[i] += bsum[i >> 10];
  if (i == 0) rowptr[N] = EN;
}

__global__ void scatter_kernel(const int* __restrict__ ei, const int* __restrict__ rowptr,
                               int* __restrict__ cursor, int* __restrict__ csr_src,
                               int E, int N)
{
  int i = blockIdx.x * 256 + threadIdx.x;
  if (i >= E + N) return;
  int src, dst;
  if (i < E) { src = ei[i]; dst = ei[E + i]; }
  else { src = i - E; dst = i - E; }
  int pos = rowptr[dst] + atomicAdd(&cursor[dst], 1);
  csr_src[pos] = src;
}

// ---------------------------------------------------------------------------
// GAT aggregation v5 + NT agg stores: one wave per dst, <=64 VGPR,
// wave-private LDS p/src staging, 8 outstanding gathers, no barriers.
// ---------------------------------------------------------------------------
__global__ __launch_bounds__(256, 8) void gat_agg5(
    const unsigned short* __restrict__ hb, const int* __restrict__ rowptr,
    const int* __restrict__ csr_src, const float* __restrict__ aS,
    const float* __restrict__ aD, unsigned short* __restrict__ agg, int N)
{
  __shared__ float s_p[4][48][8];   // per-wave p (unnormalized), 0 for padding
  __shared__ int   s_src[4][48];    // per-wave src ids, 0 for padding
  const int wid = threadIdx.x >> 6;
  const int lane = threadIdx.x & 63;
  const int dst = blockIdx.x * 4 + wid;
  if (dst >= N) return;
  const int el = lane >> 3, hh = lane & 7;
  const int start = rowptr[dst];
  const int deg = rowptr[dst + 1] - start;
  const float adh = aD[(size_t)dst * 8 + hh];

  // pass 1: scores (src ids staged straight to LDS), per-head max
  float v_c[MAXI];
  float m = -1e30f;
#pragma unroll
  for (int i = 0; i < MAXI; ++i) {
    int e = i * 8 + el;
    int s = 0; float v = -1e30f;
    if (e < deg) {
      s = csr_src[start + e];
      v = aS[(size_t)s * 8 + hh] + adh;
      v = (v > 0.f) ? v : 0.2f * v;
    }
    if (hh == 0) s_src[wid][e] = s;
    v_c[i] = v;
    m = fmaxf(m, v);
  }
  for (int e0 = MAXI * 8; e0 < deg; e0 += 8) {
    int e = e0 + el;
    if (e < deg) {
      int s = csr_src[start + e];
      float v = aS[(size_t)s * 8 + hh] + adh;
      v = (v > 0.f) ? v : 0.2f * v;
      m = fmaxf(m, v);
    }
  }
  m = fmaxf(m, __shfl_xor(m, 8));
  m = fmaxf(m, __shfl_xor(m, 16));
  m = fmaxf(m, __shfl_xor(m, 32));

  // p + stage to wave-private LDS
  float dsum = 0.f;
#pragma unroll
  for (int i = 0; i < MAXI; ++i) {
    int e = i * 8 + el;
    float p = (e < deg && v_c[i] > -1e29f) ? __expf(v_c[i] - m) : 0.f;
    dsum += p;
    s_p[wid][e][hh] = p;
  }

  // pass 2: batched gather + FMA (p=0 padding, src=0 padding -> branch-free)
  float accx[8], accy[8];
#pragma unroll
  for (int q = 0; q < 8; ++q) { accx[q] = 0.f; accy[q] = 0.f; }
  const unsigned* hb32 = (const unsigned*)hb;
  const int ng = (deg < MAXI * 8) ? ((deg + 7) >> 3) : MAXI;

  for (int i = 0; i < ng; ++i) {
    int4 sa = *(const int4*)&s_src[wid][i * 8];
    int4 sb = *(const int4*)&s_src[wid][i * 8 + 4];
    unsigned hv[8];
    hv[0] = hb32[(unsigned)sa.x * 64 + lane];
    hv[1] = hb32[(unsigned)sa.y * 64 + lane];
    hv[2] = hb32[(unsigned)sa.z * 64 + lane];
    hv[3] = hb32[(unsigned)sa.w * 64 + lane];
    hv[4] = hb32[(unsigned)sb.x * 64 + lane];
    hv[5] = hb32[(unsigned)sb.y * 64 + lane];
    hv[6] = hb32[(unsigned)sb.z * 64 + lane];
    hv[7] = hb32[(unsigned)sb.w * 64 + lane];
#pragma unroll
    for (int ee = 0; ee < 8; ++ee) {
      float4 pA = *(const float4*)&s_p[wid][i * 8 + ee][0];
      float4 pB = *(const float4*)&s_p[wid][i * 8 + ee][4];
      float hx = bf2f((unsigned short)hv[ee]);
      float hy = bf2f((unsigned short)(hv[ee] >> 16));
      accx[0] = fmaf(pA.x, hx, accx[0]); accy[0] = fmaf(pA.x, hy, accy[0]);
      accx[1] = fmaf(pA.y, hx, accx[1]); accy[1] = fmaf(pA.y, hy, accy[1]);
      accx[2] = fmaf(pA.z, hx, accx[2]); accy[2] = fmaf(pA.z, hy, accy[2]);
      accx[3] = fmaf(pA.w, hx, accx[3]); accy[3] = fmaf(pA.w, hy, accy[3]);
      accx[4] = fmaf(pB.x, hx, accx[4]); accy[4] = fmaf(pB.x, hy, accy[4]);
      accx[5] = fmaf(pB.y, hx, accx[5]); accy[5] = fmaf(pB.y, hy, accy[5]);
      accx[6] = fmaf(pB.z, hx, accx[6]); accy[6] = fmaf(pB.z, hy, accy[6]);
      accx[7] = fmaf(pB.w, hx, accx[7]); accy[7] = fmaf(pB.w, hy, accy[7]);
    }
  }
  // overflow path (deg > 48): recompute + shuffle broadcast
  const int c2 = lane * 2;
  for (int e0 = MAXI * 8; e0 < deg; e0 += 8) {
    int e = e0 + el;
    float p = 0.f; int s = 0;
    if (e < deg) {
      s = csr_src[start + e];
      float v = aS[(size_t)s * 8 + hh] + adh;
      v = (v > 0.f) ? v : 0.2f * v;
      p = __expf(v - m);
    }
    dsum += p;
    int cnt = deg - e0; if (cnt > 8) cnt = 8;
    for (int ee = 0; ee < cnt; ++ee) {
      int se = __shfl(s, ee * 8);
      unsigned hv = *(const unsigned*)&hb[(size_t)se * 128 + c2];
      float hx = bf2f((unsigned short)hv);
      float hy = bf2f((unsigned short)(hv >> 16));
#pragma unroll
      for (int q = 0; q < 8; ++q) {
        float pq = __shfl(p, ee * 8 + q);
        accx[q] = fmaf(pq, hx, accx[q]);
        accy[q] = fmaf(pq, hy, accy[q]);
      }
    }
  }

  dsum += __shfl_xor(dsum, 8);
  dsum += __shfl_xor(dsum, 16);
  dsum += __shfl_xor(dsum, 32);
  float inv = 1.f / (dsum + 1e-16f);

#pragma unroll
  for (int q = 0; q < 8; ++q) {
    float invq = __shfl(inv, q);                  // lane q holds hh=q denom
    float ax = accx[q] * invq, ay = accy[q] * invq;
    unsigned pk = ((unsigned)(unsigned short)f2bf(ay) << 16) |
                  (unsigned)(unsigned short)f2bf(ax);
    __builtin_nontemporal_store(pk, (unsigned*)&agg[(size_t)dst * 1024 + q * 128 + c2]);
  }
}

// ---------------------------------------------------------------------------
// finalize pooled, classifier MLP, softmax
// ---------------------------------------------------------------------------
__global__ __launch_bounds__(64) void classifier_kernel(
    float* __restrict__ pooled, const float* __restrict__ cnt,
    const float* __restrict__ c1W, const float* __restrict__ c1b,
    const float* __restrict__ c2W, const float* __restrict__ c2b,
    float* __restrict__ logits, float* __restrict__ preds)
{
  int g = blockIdx.x, j = threadIdx.x;
  __shared__ float sp[128];
  __shared__ float hid[64];
  __shared__ float lg[3];
  float invc = 1.f / fmaxf(cnt[g], 1.f);
  float p0 = pooled[(size_t)g * 128 + j] * invc;
  float p1 = pooled[(size_t)g * 128 + 64 + j] * invc;
  pooled[(size_t)g * 128 + j] = p0;
  pooled[(size_t)g * 128 + 64 + j] = p1;
  sp[j] = p0; sp[j + 64] = p1;
  __syncthreads();
  float a = c1b[j];
#pragma unroll
  for (int k = 0; k < 128; ++k) a = fmaf(sp[k], c1W[k * 64 + j], a);
  hid[j] = fmaxf(a, 0.f);
  __syncthreads();
  if (j < NCLS) {
    float t = c2b[j];
#pragma unroll
    for (int k = 0; k < 64; ++k) t = fmaf(hid[k], c2W[k * NCLS + j], t);
    logits[(size_t)g * NCLS + j] = t;
    lg[j] = t;
  }
  __syncthreads();
  if (j < NCLS) {
    float mx = fmaxf(lg[0], fmaxf(lg[1], lg[2]));
    float e0 = __expf(lg[0] - mx), e1 = __expf(lg[1] - mx), e2 = __expf(lg[2] - mx);
    float mine = (j == 0) ? e0 : ((j == 1) ? e1 : e2);
    preds[(size_t)g * NCLS + j] = mine / (e0 + e1 + e2);
  }
}

// ---------------------------------------------------------------------------
extern "C" void kernel_launch(void* const* d_in, const int* in_sizes, int n_in,
                              void* d_out, int out_size, void* d_ws, size_t ws_size,
                              hipStream_t stream)
{
  const float* x       = (const float*)d_in[0];
  const int*   ei      = (const int*)d_in[1];
  const int*   batch   = (const int*)d_in[2];
  const float* memory  = (const float*)d_in[3];
  const float* enc_W   = (const float*)d_in[4];
  const float* enc_b   = (const float*)d_in[5];
  const float* gat_W   = (const float*)d_in[6];   // [NL,128,1024]
  const float* att_src = (const float*)d_in[7];
  const float* att_dst = (const float*)d_in[8];
  const float* gat_b   = (const float*)d_in[9];
  const float* W_ih    = (const float*)d_in[10];
  const float* W_hh    = (const float*)d_in[11];
  const float* b_ih    = (const float*)d_in[12];
  const float* b_hh    = (const float*)d_in[13];
  const float* c1W     = (const float*)d_in[14];
  const float* c1b     = (const float*)d_in[15];
  const float* c2W     = (const float*)d_in[16];
  const float* c2b     = (const float*)d_in[17];

  const int N = in_sizes[0] / HIDC;
  const int E = in_sizes[1] / 2;
  const int EN = E + N;
  const int NB = (N + 1023) / 1024;

  char* ws = (char*)d_ws;
  size_t off = 0;
  auto alloc = [&](size_t bytes) -> void* {
    void* p = ws + off;
    off += (bytes + 255) & ~(size_t)255;
    return p;
  };
  unsigned short* hb0 = (unsigned short*)alloc((size_t)N * HIDC * 2);
  unsigned short* hb1 = (unsigned short*)alloc((size_t)N * HIDC * 2);
  unsigned short* agg = (unsigned short*)alloc((size_t)N * 1024 * 2);  // also S[N,512]
  float* aS     = (float*)alloc((size_t)N * NHEAD * 4);
  float* aD     = (float*)alloc((size_t)N * NHEAD * 4);
  short* encT   = (short*)alloc((size_t)128 * 128 * 2);
  short* Wp     = (short*)alloc((size_t)NLAY * 131072 * 2);
  float* waSD   = (float*)alloc((size_t)NLAY * 2048 * 4);
  short* Bt512  = (short*)alloc((size_t)512 * 256 * 2);
  int*   rowptr = (int*)alloc((size_t)(N + 1) * 4);
  // cursor + degtmp adjacent -> single memset
  size_t zoff0 = off;
  int*   cursor = (int*)alloc((size_t)N * 4);
  int*   degtmp = (int*)alloc((size_t)N * 4);
  size_t zbytes = off - zoff0;
  int*   bsum   = (int*)alloc(64 * 4);
  int*   csr    = (int*)alloc((size_t)EN * 4);
  float* cntbuf = (float*)alloc(64 * 4);

  float* out_logits = (float*)d_out;
  float* out_pooled = (float*)d_out + NGRAPH * NCLS;
  float* out_preds  = (float*)d_out + NGRAPH * NCLS + NGRAPH * HIDC;

  hipMemsetAsync(d_out, 0, (size_t)out_size * 4, stream);
  hipMemsetAsync(cntbuf, 0, 64 * 4, stream);
  hipMemsetAsync(cursor, 0, zbytes, stream);

  // CSR build
  hist_kernel<<<(EN + 255) / 256, 256, 0, stream>>>(ei, degtmp, E, N);
  scan1_kernel<<<NB, 1024, 0, stream>>>(degtmp, rowptr, bsum, N);
  scan2_kernel<<<1, 64, 0, stream>>>(bsum, NB);
  scan3_kernel<<<(N + 255) / 256, 256, 0, stream>>>(rowptr, bsum, N, EN);
  scatter_kernel<<<(EN + 255) / 256, 256, 0, stream>>>(ei, rowptr, cursor, csr, E, N);

  // weight prep
  convt_kernel<<<(128 * 128 + 255) / 256, 256, 0, stream>>>(enc_W, encT, 128, 128);
  rearr_kernel<<<(NLAY * 131072 + 255) / 256, 256, 0, stream>>>(gat_W, Wp);
  {
    dim3 g(NLAY, 8);
    wa_kernel<<<g, 256, 0, stream>>>(gat_W, att_src, att_dst, waSD);
  }
  build_gru_B<<<(512 * 256 + 255) / 256, 256, 0, stream>>>(W_ih, W_hh, Bt512);

  // encoder: hb0 = bf16(relu(x @ enc_W + enc_b))
  {
    dim3 g((N + 63) / 64, 2);
    mm_bf16<<<g, 256, 0, stream>>>(x, encT, enc_b, hb0, N, HIDC, 1);
  }

  unsigned short* hbcur = hb0;
  unsigned short* hbnxt = hb1;
  for (int l = 0; l < NLAY; ++l) {
    alpha2b_kernel<<<(N + 15) / 16, 256, 0, stream>>>(
        hbcur, waSD + (size_t)l * 2048, aS, aD, N);
    gat_agg5<<<(N + 3) / 4, 256, 0, stream>>>(hbcur, rowptr, csr, aS, aD, agg, N);
    mm_direct<<<(N + 63) / 64, 256, 0, stream>>>(
        agg, Wp + (size_t)l * 131072, gat_b + (size_t)l * HIDC, hbnxt,
        N, 1024, (l < NLAY - 1) ? 1 : 0);
    unsigned short* tb = hbcur; hbcur = hbnxt; hbnxt = tb;
  }

  // fused-weight GRU: S = [hb|mem] @ Bt512^T (bf16), then gates+pool fused
  {
    dim3 g((N + 63) / 64, 4);
    gru_mm_direct<<<g, 256, 0, stream>>>(hbcur, memory, Bt512, agg, N);  // agg = S
  }
  gru_gate_pool<<<(N + 127) / 128, 128, 0, stream>>>(agg, memory, b_ih, b_hh, batch,
                                                     out_pooled, cntbuf, N);

  classifier_kernel<<<NGRAPH, 64, 0, stream>>>(out_pooled, cntbuf, c1W, c1b, c2W, c2b,
                                               out_logits, out_preds);
}

// Round 10
// 863.311 us; speedup vs baseline: 1.2099x; 1.2099x over previous
//
#include <hip/hip_runtime.h>
#include <cstdint>
#include <cstddef>

#define HIDC 128
#define NHEAD 8
#define NLAY 3
#define NGRAPH 64
#define NCLS 3
#define MAXI 6   // fast path deg <= 48

typedef __attribute__((ext_vector_type(8))) short short8;
typedef __attribute__((ext_vector_type(4))) float floatx4;

__device__ inline short f2bf(float x) {
  unsigned u = __float_as_uint(x);
  unsigned r = (u + 0x7fff + ((u >> 16) & 1)) >> 16;   // RNE
  return (short)r;
}
__device__ inline float bf2f(unsigned short u) {
  return __uint_as_float(((unsigned)u) << 16);
}

// ---------------------------------------------------------------------------
// Weight prep
// ---------------------------------------------------------------------------
__global__ void convt_kernel(const float* __restrict__ W, short* __restrict__ Wt,
                             int K, int Nc)
{
  int i = blockIdx.x * 256 + threadIdx.x;
  if (i >= K * Nc) return;
  int k = i / Nc, n = i - k * Nc;
  Wt[(size_t)n * K + k] = f2bf(W[i]);
}

// Wp[l][c][h*128+k] = gat_W[l][k][h*128+c] / 8   (head-mean folded in)
__global__ void rearr_kernel(const float* __restrict__ gat_W, short* __restrict__ Wp)
{
  int i = blockIdx.x * 256 + threadIdx.x;
  if (i >= NLAY * 131072) return;
  int l = i >> 17, rem = i & 131071;
  int k = rem >> 10, hc = rem & 1023;
  int hh = hc >> 7, cc = hc & 127;
  Wp[(size_t)l * 131072 + (size_t)cc * 1024 + hh * 128 + k] = f2bf(gat_W[i] * 0.125f);
}

// waSD[l][k][j16]: j16<8 -> W_h a_src_h projection, j16>=8 -> a_dst
__global__ __launch_bounds__(256) void wa_kernel(
    const float* __restrict__ gat_W, const float* __restrict__ att_src,
    const float* __restrict__ att_dst, float* __restrict__ waSD)
{
  int l = blockIdx.x;
  int idx = blockIdx.y * 256 + threadIdx.x;
  int k = idx >> 4, j16 = idx & 15;
  int hh = j16 & 7;
  const float* a = ((j16 < 8) ? att_src : att_dst) + (size_t)l * 1024 + hh * 128;
  const float* w = gat_W + (size_t)l * 131072 + (size_t)k * 1024 + hh * 128;
  float s = 0.f;
  for (int cc = 0; cc < 128; ++cc) s += w[cc] * a[cc];
  waSD[(size_t)l * 2048 + idx] = s;
}

// Bt512[col][k] for fused GRU matmul over A=[h_bf16 | mem_bf16] (K=256)
__global__ void build_gru_B(const float* __restrict__ W_ih,
                            const float* __restrict__ W_hh,
                            short* __restrict__ Bt512)
{
  int i = blockIdx.x * 256 + threadIdx.x;
  if (i >= 512 * 256) return;
  int col = i >> 8, k = i & 255;
  float v;
  if (k < 128) {
    if (col < 384) v = W_ih[(size_t)col * 128 + k];
    else v = 0.f;
  } else {
    int k2 = k - 128;
    if (col < 256) v = W_hh[(size_t)col * 128 + k2];
    else if (col < 384) v = 0.f;
    else v = W_hh[(size_t)(col - 128) * 128 + k2];
  }
  Bt512[i] = f2bf(v);
}

// ---------------------------------------------------------------------------
// Encoder: C[M,Nc] = relu(A_fp32[M,128] @ B + bias), Bt[Nc][128] bf16.
// ---------------------------------------------------------------------------
__global__ __launch_bounds__(256) void mm_bf16(
    const float* __restrict__ A, const short* __restrict__ Bt,
    const float* __restrict__ bias, unsigned short* __restrict__ Cb2,
    int M, int Nc, int relu)
{
  __shared__ short Asl[64 * 136];
  const int tid = threadIdx.x;
  const int m0 = blockIdx.x * 64;
  const int n0 = blockIdx.y * 64;

  const float4* A4 = (const float4*)A;
#pragma unroll
  for (int it = 0; it < 8; ++it) {
    int idx = tid + it * 256;
    int r = idx >> 5, k4 = idx & 31;
    int row = m0 + r; if (row >= M) row = M - 1;
    float4 a = A4[(size_t)row * 32 + k4];
    ushort4 p;
    p.x = (unsigned short)f2bf(a.x); p.y = (unsigned short)f2bf(a.y);
    p.z = (unsigned short)f2bf(a.z); p.w = (unsigned short)f2bf(a.w);
    *(ushort4*)&Asl[r * 136 + k4 * 4] = p;
  }
  __syncthreads();

  const int wid = tid >> 6, lane = tid & 63;
  const int l15 = lane & 15, quad = lane >> 4;
  const int wm = wid & 1, wn = wid >> 1;
  const int mb = wm * 32;
  const int nb = n0 + wn * 32;

  floatx4 acc00 = {0.f, 0.f, 0.f, 0.f};
  floatx4 acc01 = acc00, acc10 = acc00, acc11 = acc00;

#pragma unroll
  for (int kk = 0; kk < 4; ++kk) {
    int k = kk * 32 + quad * 8;
    short8 a0 = *(const short8*)&Asl[(mb + l15) * 136 + k];
    short8 a1 = *(const short8*)&Asl[(mb + 16 + l15) * 136 + k];
    short8 b0 = *(const short8*)&Bt[(size_t)(nb + l15) * 128 + k];
    short8 b1 = *(const short8*)&Bt[(size_t)(nb + 16 + l15) * 128 + k];
    acc00 = __builtin_amdgcn_mfma_f32_16x16x32_bf16(a0, b0, acc00, 0, 0, 0);
    acc01 = __builtin_amdgcn_mfma_f32_16x16x32_bf16(a0, b1, acc01, 0, 0, 0);
    acc10 = __builtin_amdgcn_mfma_f32_16x16x32_bf16(a1, b0, acc10, 0, 0, 0);
    acc11 = __builtin_amdgcn_mfma_f32_16x16x32_bf16(a1, b1, acc11, 0, 0, 0);
  }

#pragma unroll
  for (int mt = 0; mt < 2; ++mt) {
#pragma unroll
    for (int nt = 0; nt < 2; ++nt) {
      floatx4 acc = (mt == 0) ? (nt == 0 ? acc00 : acc01)
                              : (nt == 0 ? acc10 : acc11);
      int colg = nb + nt * 16 + l15;
      float bv = bias ? bias[colg] : 0.f;
#pragma unroll
      for (int r = 0; r < 4; ++r) {
        int rowg = m0 + mb + mt * 16 + quad * 4 + r;
        if (rowg < M && colg < Nc) {
          float v = acc[r] + bv;
          if (relu) v = fmaxf(v, 0.f);
          Cb2[(size_t)rowg * Nc + colg] = (unsigned short)f2bf(v);
        }
      }
    }
  }
}

// ---------------------------------------------------------------------------
// C[M,128] = act(A_bf16[M,K] @ B + bias), Bt[128][K] bf16, K mult of 64.
// LDS-staged A (proven round-7 version). bf16 output.
// ---------------------------------------------------------------------------
__global__ __launch_bounds__(256) void mm_bf16A(
    const unsigned short* __restrict__ A, const short* __restrict__ Bt,
    const float* __restrict__ bias, unsigned short* __restrict__ Cb2,
    int M, int Nc, int K, int relu)
{
  __shared__ short As[64 * 72];
  const int tid = threadIdx.x;
  const int m0 = blockIdx.x * 64;
  const int n0 = blockIdx.y * 128;
  const int wid = tid >> 6, lane = tid & 63;
  const int l15 = lane & 15, quad = lane >> 4;
  const int wm = wid & 1, wn = wid >> 1;
  const int mb = wm * 32;
  const int nb = n0 + wn * 64;

  floatx4 acc[2][4];
#pragma unroll
  for (int a = 0; a < 2; ++a)
#pragma unroll
    for (int g = 0; g < 4; ++g) acc[a][g] = (floatx4){0.f, 0.f, 0.f, 0.f};

  for (int kb = 0; kb < K; kb += 64) {
    __syncthreads();
#pragma unroll
    for (int it = 0; it < 2; ++it) {
      int idx = tid + it * 256;
      int r = idx >> 3, k8 = (idx & 7) * 8;
      int row = m0 + r; if (row >= M) row = M - 1;
      *(short8*)&As[r * 72 + k8] = *(const short8*)&A[(size_t)row * K + kb + k8];
    }
    __syncthreads();
#pragma unroll
    for (int kk = 0; kk < 2; ++kk) {
      int ko = kk * 32 + quad * 8;
      short8 a0 = *(const short8*)&As[(mb + l15) * 72 + ko];
      short8 a1 = *(const short8*)&As[(mb + 16 + l15) * 72 + ko];
#pragma unroll
      for (int g = 0; g < 4; ++g) {
        int col = nb + g * 16 + l15; if (col >= Nc) col = Nc - 1;
        short8 b = *(const short8*)&Bt[(size_t)col * K + kb + ko];
        acc[0][g] = __builtin_amdgcn_mfma_f32_16x16x32_bf16(a0, b, acc[0][g], 0, 0, 0);
        acc[1][g] = __builtin_amdgcn_mfma_f32_16x16x32_bf16(a1, b, acc[1][g], 0, 0, 0);
      }
    }
  }

#pragma unroll
  for (int mt = 0; mt < 2; ++mt) {
#pragma unroll
    for (int g = 0; g < 4; ++g) {
      int colg = nb + g * 16 + l15;
      if (colg >= Nc) continue;
      float bv = bias[colg];
#pragma unroll
      for (int r = 0; r < 4; ++r) {
        int rowg = m0 + mb + mt * 16 + quad * 4 + r;
        if (rowg < M) {
          float v = acc[mt][g][r] + bv;
          if (relu) v = fmaxf(v, 0.f);
          Cb2[(size_t)rowg * Nc + colg] = (unsigned short)f2bf(v);
        }
      }
    }
  }
}

// ---------------------------------------------------------------------------
// GRU matmul: S[M,512] = [hb | mem_fp32->bf16] @ Bt512^T, K=256. Out bf16.
// LDS-staged (proven round-7 version).
// ---------------------------------------------------------------------------
__global__ __launch_bounds__(256) void gru_mm(
    const unsigned short* __restrict__ hb, const float* __restrict__ mem,
    const short* __restrict__ Bt512, unsigned short* __restrict__ S, int M)
{
  __shared__ short As[64 * 72];
  const int tid = threadIdx.x;
  const int m0 = blockIdx.x * 64;
  const int n0 = blockIdx.y * 128;
  const int wid = tid >> 6, lane = tid & 63;
  const int l15 = lane & 15, quad = lane >> 4;
  const int wm = wid & 1, wn = wid >> 1;
  const int mb = wm * 32;
  const int nb = n0 + wn * 64;

  floatx4 acc[2][4];
#pragma unroll
  for (int a = 0; a < 2; ++a)
#pragma unroll
    for (int g = 0; g < 4; ++g) acc[a][g] = (floatx4){0.f, 0.f, 0.f, 0.f};

  for (int kb = 0; kb < 256; kb += 64) {
    __syncthreads();
#pragma unroll
    for (int it = 0; it < 2; ++it) {
      int idx = tid + it * 256;
      int r = idx >> 3, k8 = (idx & 7) * 8;
      int row = m0 + r; if (row >= M) row = M - 1;
      if (kb < 128) {
        *(short8*)&As[r * 72 + k8] = *(const short8*)&hb[(size_t)row * 128 + kb + k8];
      } else {
        const float4* m4 = (const float4*)(mem + (size_t)row * 128 + (kb - 128) + k8);
        float4 a = m4[0], b = m4[1];
        short8 p;
        p[0] = f2bf(a.x); p[1] = f2bf(a.y); p[2] = f2bf(a.z); p[3] = f2bf(a.w);
        p[4] = f2bf(b.x); p[5] = f2bf(b.y); p[6] = f2bf(b.z); p[7] = f2bf(b.w);
        *(short8*)&As[r * 72 + k8] = p;
      }
    }
    __syncthreads();
#pragma unroll
    for (int kk = 0; kk < 2; ++kk) {
      int ko = kk * 32 + quad * 8;
      short8 a0 = *(const short8*)&As[(mb + l15) * 72 + ko];
      short8 a1 = *(const short8*)&As[(mb + 16 + l15) * 72 + ko];
#pragma unroll
      for (int g = 0; g < 4; ++g) {
        int col = nb + g * 16 + l15;
        short8 b = *(const short8*)&Bt512[(size_t)col * 256 + kb + ko];
        acc[0][g] = __builtin_amdgcn_mfma_f32_16x16x32_bf16(a0, b, acc[0][g], 0, 0, 0);
        acc[1][g] = __builtin_amdgcn_mfma_f32_16x16x32_bf16(a1, b, acc[1][g], 0, 0, 0);
      }
    }
  }

#pragma unroll
  for (int mt = 0; mt < 2; ++mt) {
#pragma unroll
    for (int g = 0; g < 4; ++g) {
      int colg = nb + g * 16 + l15;
#pragma unroll
      for (int r = 0; r < 4; ++r) {
        int rowg = m0 + mb + mt * 16 + quad * 4 + r;
        if (rowg < M)
          S[(size_t)rowg * 512 + colg] = (unsigned short)f2bf(acc[mt][g][r]);
      }
    }
  }
}

// ---------------------------------------------------------------------------
// Fused GRU gates + global_mean_pool (run-length accumulate, atomic flush)
// ---------------------------------------------------------------------------
__global__ __launch_bounds__(128) void gru_gate_pool(
    const unsigned short* __restrict__ S, const float* __restrict__ mem,
    const float* __restrict__ bI, const float* __restrict__ bH,
    const int* __restrict__ batch, float* __restrict__ pooled_sums,
    float* __restrict__ cnt, int N)
{
  int n0 = blockIdx.x * 128;
  int c = threadIdx.x;
  if (n0 >= N) return;
  int end = n0 + 128; if (end > N) end = N;
  const float bIr = bI[c],       bHr = bH[c];
  const float bIz = bI[128 + c], bHz = bH[128 + c];
  const float bIn = bI[256 + c], bHn = bH[256 + c];
  int cur = batch[n0];
  float acc = 0.f, count = 0.f;
  for (int n = n0; n < end; ++n) {
    int b = batch[n];
    if (b != cur) {
      atomicAdd(&pooled_sums[(size_t)cur * HIDC + c], acc);
      if (c == 0) atomicAdd(&cnt[cur], count);
      acc = 0.f; count = 0.f; cur = b;
    }
    size_t base = (size_t)n * 512;
    float sr  = bf2f(S[base + c])       + bIr + bHr;
    float sz  = bf2f(S[base + 128 + c]) + bIz + bHz;
    float gin = bf2f(S[base + 256 + c]) + bIn;
    float ghn = bf2f(S[base + 384 + c]) + bHn;
    float rg = 1.f / (1.f + __expf(-sr));
    float zg = 1.f / (1.f + __expf(-sz));
    float nc = tanhf(gin + rg * ghn);
    float hv = (1.f - zg) * nc + zg * mem[(size_t)n * 128 + c];
    acc += hv; count += 1.f;
  }
  atomicAdd(&pooled_sums[(size_t)cur * HIDC + c], acc);
  if (c == 0) atomicAdd(&cnt[cur], count);
}

// ---------------------------------------------------------------------------
// alphas from bf16 h: aS/aD[n][h] = h[n,:] . waSD[:,j16]
// ---------------------------------------------------------------------------
__global__ __launch_bounds__(256) void alpha2b_kernel(
    const unsigned short* __restrict__ hb, const float* __restrict__ waSD,
    float* __restrict__ aS, float* __restrict__ aD, int N)
{
  __shared__ float s_wa[2048];
  const int tid = threadIdx.x;
  for (int i = tid; i < 2048; i += 256) s_wa[i] = waSD[i];
  __syncthreads();
  int node = blockIdx.x * 16 + (tid >> 4);
  int j = tid & 15;
  if (node >= N) return;
  const short8* h8 = (const short8*)(hb + (size_t)node * 128);
  float s = 0.f;
#pragma unroll
  for (int k8 = 0; k8 < 16; ++k8) {
    short8 v = h8[k8];
#pragma unroll
    for (int t = 0; t < 8; ++t)
      s += bf2f((unsigned short)v[t]) * s_wa[(k8 * 8 + t) * 16 + j];
  }
  if (j < 8) aS[(size_t)node * 8 + j] = s;
  else       aD[(size_t)node * 8 + (j - 8)] = s;
}

// ---------------------------------------------------------------------------
// CSR build: histogram, 3-stage scan, scatter
// ---------------------------------------------------------------------------
__global__ void hist_kernel(const int* __restrict__ ei, int* __restrict__ deg, int E, int N)
{
  int i = blockIdx.x * 256 + threadIdx.x;
  if (i >= E + N) return;
  int dst = (i < E) ? ei[E + i] : (i - E);
  atomicAdd(&deg[dst], 1);
}

__global__ __launch_bounds__(1024) void scan1_kernel(
    const int* __restrict__ deg, int* __restrict__ rowptr,
    int* __restrict__ bsum, int N)
{
  __shared__ int sd[1024];
  int i = blockIdx.x * 1024 + threadIdx.x;
  int v = (i < N) ? deg[i] : 0;
  sd[threadIdx.x] = v;
  __syncthreads();
  for (int off = 1; off < 1024; off <<= 1) {
    int t = (threadIdx.x >= off) ? sd[threadIdx.x - off] : 0;
    __syncthreads();
    sd[threadIdx.x] += t;
    __syncthreads();
  }
  if (i < N) rowptr[i] = sd[threadIdx.x] - v;
  if (threadIdx.x == 1023) bsum[blockIdx.x] = sd[1023];
}

__global__ __launch_bounds__(64) void scan2_kernel(int* __restrict__ bsum, int nb)
{
  int lane = threadIdx.x;
  int v = (lane < nb) ? bsum[lane] : 0;
  int incl = v;
  for (int off = 1; off < 64; off <<= 1) {
    int t = __shfl_up(incl, off);
    if (lane >= off) incl += t;
  }
  if (lane < nb) bsum[lane] = incl - v;
}

__global__ void scan3_kernel(int* __restrict__ rowptr, const int* __restrict__ bsum,
                             int N, int EN)
{
  int i = blockIdx.x * 256 + threadIdx.x;
  if (i < N) rowptr[i] += bsum[i >> 10];
  if (i == 0) rowptr[N] = EN;
}

__global__ void scatter_kernel(const int* __restrict__ ei, const int* __restrict__ rowptr,
                               int* __restrict__ cursor, int* __restrict__ csr_src,
                               int E, int N)
{
  int i = blockIdx.x * 256 + threadIdx.x;
  if (i >= E + N) return;
  int src, dst;
  if (i < E) { src = ei[i]; dst = ei[E + i]; }
  else { src = i - E; dst = i - E; }
  int pos = rowptr[dst] + atomicAdd(&cursor[dst], 1);
  csr_src[pos] = src;
}

// ---------------------------------------------------------------------------
// GAT aggregation v5 (proven round-7 version): one wave per dst, <=64 VGPR,
// wave-private LDS p/src staging, 8 outstanding gathers, no barriers.
// ---------------------------------------------------------------------------
__global__ __launch_bounds__(256, 8) void gat_agg5(
    const unsigned short* __restrict__ hb, const int* __restrict__ rowptr,
    const int* __restrict__ csr_src, const float* __restrict__ aS,
    const float* __restrict__ aD, unsigned short* __restrict__ agg, int N)
{
  __shared__ float s_p[4][48][8];   // per-wave p (unnormalized), 0 for padding
  __shared__ int   s_src[4][48];    // per-wave src ids, 0 for padding
  const int wid = threadIdx.x >> 6;
  const int lane = threadIdx.x & 63;
  const int dst = blockIdx.x * 4 + wid;
  if (dst >= N) return;
  const int el = lane >> 3, hh = lane & 7;
  const int start = rowptr[dst];
  const int deg = rowptr[dst + 1] - start;
  const float adh = aD[(size_t)dst * 8 + hh];

  // pass 1: scores (src ids staged straight to LDS), per-head max
  float v_c[MAXI];
  float m = -1e30f;
#pragma unroll
  for (int i = 0; i < MAXI; ++i) {
    int e = i * 8 + el;
    int s = 0; float v = -1e30f;
    if (e < deg) {
      s = csr_src[start + e];
      v = aS[(size_t)s * 8 + hh] + adh;
      v = (v > 0.f) ? v : 0.2f * v;
    }
    if (hh == 0) s_src[wid][e] = s;
    v_c[i] = v;
    m = fmaxf(m, v);
  }
  for (int e0 = MAXI * 8; e0 < deg; e0 += 8) {
    int e = e0 + el;
    if (e < deg) {
      int s = csr_src[start + e];
      float v = aS[(size_t)s * 8 + hh] + adh;
      v = (v > 0.f) ? v : 0.2f * v;
      m = fmaxf(m, v);
    }
  }
  m = fmaxf(m, __shfl_xor(m, 8));
  m = fmaxf(m, __shfl_xor(m, 16));
  m = fmaxf(m, __shfl_xor(m, 32));

  // p + stage to wave-private LDS
  float dsum = 0.f;
#pragma unroll
  for (int i = 0; i < MAXI; ++i) {
    int e = i * 8 + el;
    float p = (e < deg && v_c[i] > -1e29f) ? __expf(v_c[i] - m) : 0.f;
    dsum += p;
    s_p[wid][e][hh] = p;
  }

  // pass 2: batched gather + FMA (p=0 padding, src=0 padding -> branch-free)
  float accx[8], accy[8];
#pragma unroll
  for (int q = 0; q < 8; ++q) { accx[q] = 0.f; accy[q] = 0.f; }
  const unsigned* hb32 = (const unsigned*)hb;
  const int ng = (deg < MAXI * 8) ? ((deg + 7) >> 3) : MAXI;

  for (int i = 0; i < ng; ++i) {
    int4 sa = *(const int4*)&s_src[wid][i * 8];
    int4 sb = *(const int4*)&s_src[wid][i * 8 + 4];
    unsigned hv[8];
    hv[0] = hb32[(unsigned)sa.x * 64 + lane];
    hv[1] = hb32[(unsigned)sa.y * 64 + lane];
    hv[2] = hb32[(unsigned)sa.z * 64 + lane];
    hv[3] = hb32[(unsigned)sa.w * 64 + lane];
    hv[4] = hb32[(unsigned)sb.x * 64 + lane];
    hv[5] = hb32[(unsigned)sb.y * 64 + lane];
    hv[6] = hb32[(unsigned)sb.z * 64 + lane];
    hv[7] = hb32[(unsigned)sb.w * 64 + lane];
#pragma unroll
    for (int ee = 0; ee < 8; ++ee) {
      float4 pA = *(const float4*)&s_p[wid][i * 8 + ee][0];
      float4 pB = *(const float4*)&s_p[wid][i * 8 + ee][4];
      float hx = bf2f((unsigned short)hv[ee]);
      float hy = bf2f((unsigned short)(hv[ee] >> 16));
      accx[0] = fmaf(pA.x, hx, accx[0]); accy[0] = fmaf(pA.x, hy, accy[0]);
      accx[1] = fmaf(pA.y, hx, accx[1]); accy[1] = fmaf(pA.y, hy, accy[1]);
      accx[2] = fmaf(pA.z, hx, accx[2]); accy[2] = fmaf(pA.z, hy, accy[2]);
      accx[3] = fmaf(pA.w, hx, accx[3]); accy[3] = fmaf(pA.w, hy, accy[3]);
      accx[4] = fmaf(pB.x, hx, accx[4]); accy[4] = fmaf(pB.x, hy, accy[4]);
      accx[5] = fmaf(pB.y, hx, accx[5]); accy[5] = fmaf(pB.y, hy, accy[5]);
      accx[6] = fmaf(pB.z, hx, accx[6]); accy[6] = fmaf(pB.z, hy, accy[6]);
      accx[7] = fmaf(pB.w, hx, accx[7]); accy[7] = fmaf(pB.w, hy, accy[7]);
    }
  }
  // overflow path (deg > 48): recompute + shuffle broadcast
  const int c2 = lane * 2;
  for (int e0 = MAXI * 8; e0 < deg; e0 += 8) {
    int e = e0 + el;
    float p = 0.f; int s = 0;
    if (e < deg) {
      s = csr_src[start + e];
      float v = aS[(size_t)s * 8 + hh] + adh;
      v = (v > 0.f) ? v : 0.2f * v;
      p = __expf(v - m);
    }
    dsum += p;
    int cnt = deg - e0; if (cnt > 8) cnt = 8;
    for (int ee = 0; ee < cnt; ++ee) {
      int se = __shfl(s, ee * 8);
      unsigned hv = *(const unsigned*)&hb[(size_t)se * 128 + c2];
      float hx = bf2f((unsigned short)hv);
      float hy = bf2f((unsigned short)(hv >> 16));
#pragma unroll
      for (int q = 0; q < 8; ++q) {
        float pq = __shfl(p, ee * 8 + q);
        accx[q] = fmaf(pq, hx, accx[q]);
        accy[q] = fmaf(pq, hy, accy[q]);
      }
    }
  }

  dsum += __shfl_xor(dsum, 8);
  dsum += __shfl_xor(dsum, 16);
  dsum += __shfl_xor(dsum, 32);
  float inv = 1.f / (dsum + 1e-16f);

#pragma unroll
  for (int q = 0; q < 8; ++q) {
    float invq = __shfl(inv, q);                  // lane q holds hh=q denom
    float ax = accx[q] * invq, ay = accy[q] * invq;
    unsigned pk = ((unsigned)(unsigned short)f2bf(ay) << 16) |
                  (unsigned)(unsigned short)f2bf(ax);
    *(unsigned*)&agg[(size_t)dst * 1024 + q * 128 + c2] = pk;
  }
}

// ---------------------------------------------------------------------------
// finalize pooled, classifier MLP, softmax
// ---------------------------------------------------------------------------
__global__ __launch_bounds__(64) void classifier_kernel(
    float* __restrict__ pooled, const float* __restrict__ cnt,
    const float* __restrict__ c1W, const float* __restrict__ c1b,
    const float* __restrict__ c2W, const float* __restrict__ c2b,
    float* __restrict__ logits, float* __restrict__ preds)
{
  int g = blockIdx.x, j = threadIdx.x;
  __shared__ float sp[128];
  __shared__ float hid[64];
  __shared__ float lg[3];
  float invc = 1.f / fmaxf(cnt[g], 1.f);
  float p0 = pooled[(size_t)g * 128 + j] * invc;
  float p1 = pooled[(size_t)g * 128 + 64 + j] * invc;
  pooled[(size_t)g * 128 + j] = p0;
  pooled[(size_t)g * 128 + 64 + j] = p1;
  sp[j] = p0; sp[j + 64] = p1;
  __syncthreads();
  float a = c1b[j];
#pragma unroll
  for (int k = 0; k < 128; ++k) a = fmaf(sp[k], c1W[k * 64 + j], a);
  hid[j] = fmaxf(a, 0.f);
  __syncthreads();
  if (j < NCLS) {
    float t = c2b[j];
#pragma unroll
    for (int k = 0; k < 64; ++k) t = fmaf(hid[k], c2W[k * NCLS + j], t);
    logits[(size_t)g * NCLS + j] = t;
    lg[j] = t;
  }
  __syncthreads();
  if (j < NCLS) {
    float mx = fmaxf(lg[0], fmaxf(lg[1], lg[2]));
    float e0 = __expf(lg[0] - mx), e1 = __expf(lg[1] - mx), e2 = __expf(lg[2] - mx);
    float mine = (j == 0) ? e0 : ((j == 1) ? e1 : e2);
    preds[(size_t)g * NCLS + j] = mine / (e0 + e1 + e2);
  }
}

// ---------------------------------------------------------------------------
extern "C" void kernel_launch(void* const* d_in, const int* in_sizes, int n_in,
                              void* d_out, int out_size, void* d_ws, size_t ws_size,
                              hipStream_t stream)
{
  const float* x       = (const float*)d_in[0];
  const int*   ei      = (const int*)d_in[1];
  const int*   batch   = (const int*)d_in[2];
  const float* memory  = (const float*)d_in[3];
  const float* enc_W   = (const float*)d_in[4];
  const float* enc_b   = (const float*)d_in[5];
  const float* gat_W   = (const float*)d_in[6];   // [NL,128,1024]
  const float* att_src = (const float*)d_in[7];
  const float* att_dst = (const float*)d_in[8];
  const float* gat_b   = (const float*)d_in[9];
  const float* W_ih    = (const float*)d_in[10];
  const float* W_hh    = (const float*)d_in[11];
  const float* b_ih    = (const float*)d_in[12];
  const float* b_hh    = (const float*)d_in[13];
  const float* c1W     = (const float*)d_in[14];
  const float* c1b     = (const float*)d_in[15];
  const float* c2W     = (const float*)d_in[16];
  const float* c2b     = (const float*)d_in[17];

  const int N = in_sizes[0] / HIDC;
  const int E = in_sizes[1] / 2;
  const int EN = E + N;
  const int NB = (N + 1023) / 1024;

  char* ws = (char*)d_ws;
  size_t off = 0;
  auto alloc = [&](size_t bytes) -> void* {
    void* p = ws + off;
    off += (bytes + 255) & ~(size_t)255;
    return p;
  };
  unsigned short* hb0 = (unsigned short*)alloc((size_t)N * HIDC * 2);
  unsigned short* hb1 = (unsigned short*)alloc((size_t)N * HIDC * 2);
  unsigned short* agg = (unsigned short*)alloc((size_t)N * 1024 * 2);  // also S[N,512]
  float* aS     = (float*)alloc((size_t)N * NHEAD * 4);
  float* aD     = (float*)alloc((size_t)N * NHEAD * 4);
  short* encT   = (short*)alloc((size_t)128 * 128 * 2);
  short* Wp     = (short*)alloc((size_t)NLAY * 131072 * 2);
  float* waSD   = (float*)alloc((size_t)NLAY * 2048 * 4);
  short* Bt512  = (short*)alloc((size_t)512 * 256 * 2);
  int*   rowptr = (int*)alloc((size_t)(N + 1) * 4);
  // cursor + degtmp adjacent -> single memset
  size_t zoff0 = off;
  int*   cursor = (int*)alloc((size_t)N * 4);
  int*   degtmp = (int*)alloc((size_t)N * 4);
  size_t zbytes = off - zoff0;
  int*   bsum   = (int*)alloc(64 * 4);
  int*   csr    = (int*)alloc((size_t)EN * 4);
  float* cntbuf = (float*)alloc(64 * 4);

  float* out_logits = (float*)d_out;
  float* out_pooled = (float*)d_out + NGRAPH * NCLS;
  float* out_preds  = (float*)d_out + NGRAPH * NCLS + NGRAPH * HIDC;

  hipMemsetAsync(d_out, 0, (size_t)out_size * 4, stream);
  hipMemsetAsync(cntbuf, 0, 64 * 4, stream);
  hipMemsetAsync(cursor, 0, zbytes, stream);

  // CSR build
  hist_kernel<<<(EN + 255) / 256, 256, 0, stream>>>(ei, degtmp, E, N);
  scan1_kernel<<<NB, 1024, 0, stream>>>(degtmp, rowptr, bsum, N);
  scan2_kernel<<<1, 64, 0, stream>>>(bsum, NB);
  scan3_kernel<<<(N + 255) / 256, 256, 0, stream>>>(rowptr, bsum, N, EN);
  scatter_kernel<<<(EN + 255) / 256, 256, 0, stream>>>(ei, rowptr, cursor, csr, E, N);

  // weight prep
  convt_kernel<<<(128 * 128 + 255) / 256, 256, 0, stream>>>(enc_W, encT, 128, 128);
  rearr_kernel<<<(NLAY * 131072 + 255) / 256, 256, 0, stream>>>(gat_W, Wp);
  {
    dim3 g(NLAY, 8);
    wa_kernel<<<g, 256, 0, stream>>>(gat_W, att_src, att_dst, waSD);
  }
  build_gru_B<<<(512 * 256 + 255) / 256, 256, 0, stream>>>(W_ih, W_hh, Bt512);

  // encoder: hb0 = bf16(relu(x @ enc_W + enc_b))
  {
    dim3 g((N + 63) / 64, 2);
    mm_bf16<<<g, 256, 0, stream>>>(x, encT, enc_b, hb0, N, HIDC, 1);
  }

  unsigned short* hbcur = hb0;
  unsigned short* hbnxt = hb1;
  for (int l = 0; l < NLAY; ++l) {
    alpha2b_kernel<<<(N + 15) / 16, 256, 0, stream>>>(
        hbcur, waSD + (size_t)l * 2048, aS, aD, N);
    gat_agg5<<<(N + 3) / 4, 256, 0, stream>>>(hbcur, rowptr, csr, aS, aD, agg, N);
    dim3 g((N + 63) / 64, 1);
    mm_bf16A<<<g, 256, 0, stream>>>(agg, Wp + (size_t)l * 131072,
                                    gat_b + (size_t)l * HIDC, hbnxt,
                                    N, HIDC, 1024, (l < NLAY - 1) ? 1 : 0);
    unsigned short* tb = hbcur; hbcur = hbnxt; hbnxt = tb;
  }

  // fused-weight GRU: S = [hb|mem] @ Bt512^T (bf16), then gates+pool fused
  {
    dim3 g((N + 63) / 64, 4);
    gru_mm<<<g, 256, 0, stream>>>(hbcur, memory, Bt512, agg, N);   // agg reused as S
  }
  gru_gate_pool<<<(N + 127) / 128, 128, 0, stream>>>(agg, memory, b_ih, b_hh, batch,
                                                     out_pooled, cntbuf, N);

  classifier_kernel<<<NGRAPH, 64, 0, stream>>>(out_pooled, cntbuf, c1W, c1b, c2W, c2b,
                                               out_logits, out_preds);
}

// Round 11
// 836.717 us; speedup vs baseline: 1.2484x; 1.0318x over previous
//
#include <hip/hip_runtime.h>
#include <cstdint>
#include <cstddef>

#define HIDC 128
#define NHEAD 8
#define NLAY 3
#define NGRAPH 64
#define NCLS 3
#define MAXI 6   // fast path deg <= 48
#define PCHUNK 8 // nodes per gru_gate_pool block (occupancy: 6250 blocks)

typedef __attribute__((ext_vector_type(8))) short short8;
typedef __attribute__((ext_vector_type(4))) float floatx4;

__device__ inline short f2bf(float x) {
  unsigned u = __float_as_uint(x);
  unsigned r = (u + 0x7fff + ((u >> 16) & 1)) >> 16;   // RNE
  return (short)r;
}
__device__ inline float bf2f(unsigned short u) {
  return __uint_as_float(((unsigned)u) << 16);
}

// ---------------------------------------------------------------------------
// Weight prep
// ---------------------------------------------------------------------------
__global__ void convt_kernel(const float* __restrict__ W, short* __restrict__ Wt,
                             int K, int Nc)
{
  int i = blockIdx.x * 256 + threadIdx.x;
  if (i >= K * Nc) return;
  int k = i / Nc, n = i - k * Nc;
  Wt[(size_t)n * K + k] = f2bf(W[i]);
}

// Wp[l][c][h*128+k] = gat_W[l][k][h*128+c] / 8   (head-mean folded in)
__global__ void rearr_kernel(const float* __restrict__ gat_W, short* __restrict__ Wp)
{
  int i = blockIdx.x * 256 + threadIdx.x;
  if (i >= NLAY * 131072) return;
  int l = i >> 17, rem = i & 131071;
  int k = rem >> 10, hc = rem & 1023;
  int hh = hc >> 7, cc = hc & 127;
  Wp[(size_t)l * 131072 + (size_t)cc * 1024 + hh * 128 + k] = f2bf(gat_W[i] * 0.125f);
}

// waSD[l][k][j16]: j16<8 -> W_h a_src_h projection, j16>=8 -> a_dst
__global__ __launch_bounds__(256) void wa_kernel(
    const float* __restrict__ gat_W, const float* __restrict__ att_src,
    const float* __restrict__ att_dst, float* __restrict__ waSD)
{
  int l = blockIdx.x;
  int idx = blockIdx.y * 256 + threadIdx.x;
  int k = idx >> 4, j16 = idx & 15;
  int hh = j16 & 7;
  const float* a = ((j16 < 8) ? att_src : att_dst) + (size_t)l * 1024 + hh * 128;
  const float* w = gat_W + (size_t)l * 131072 + (size_t)k * 1024 + hh * 128;
  float s = 0.f;
  for (int cc = 0; cc < 128; ++cc) s += w[cc] * a[cc];
  waSD[(size_t)l * 2048 + idx] = s;
}

// Bt512[col][k] for fused GRU matmul over A=[h_bf16 | mem_bf16] (K=256)
__global__ void build_gru_B(const float* __restrict__ W_ih,
                            const float* __restrict__ W_hh,
                            short* __restrict__ Bt512)
{
  int i = blockIdx.x * 256 + threadIdx.x;
  if (i >= 512 * 256) return;
  int col = i >> 8, k = i & 255;
  float v;
  if (k < 128) {
    if (col < 384) v = W_ih[(size_t)col * 128 + k];
    else v = 0.f;
  } else {
    int k2 = k - 128;
    if (col < 256) v = W_hh[(size_t)col * 128 + k2];
    else if (col < 384) v = 0.f;
    else v = W_hh[(size_t)(col - 128) * 128 + k2];
  }
  Bt512[i] = f2bf(v);
}

// ---------------------------------------------------------------------------
// Encoder: C[M,Nc] = relu(A_fp32[M,128] @ B + bias), Bt[Nc][128] bf16.
// ---------------------------------------------------------------------------
__global__ __launch_bounds__(256) void mm_bf16(
    const float* __restrict__ A, const short* __restrict__ Bt,
    const float* __restrict__ bias, unsigned short* __restrict__ Cb2,
    int M, int Nc, int relu)
{
  __shared__ short Asl[64 * 136];
  const int tid = threadIdx.x;
  const int m0 = blockIdx.x * 64;
  const int n0 = blockIdx.y * 64;

  const float4* A4 = (const float4*)A;
#pragma unroll
  for (int it = 0; it < 8; ++it) {
    int idx = tid + it * 256;
    int r = idx >> 5, k4 = idx & 31;
    int row = m0 + r; if (row >= M) row = M - 1;
    float4 a = A4[(size_t)row * 32 + k4];
    ushort4 p;
    p.x = (unsigned short)f2bf(a.x); p.y = (unsigned short)f2bf(a.y);
    p.z = (unsigned short)f2bf(a.z); p.w = (unsigned short)f2bf(a.w);
    *(ushort4*)&Asl[r * 136 + k4 * 4] = p;
  }
  __syncthreads();

  const int wid = tid >> 6, lane = tid & 63;
  const int l15 = lane & 15, quad = lane >> 4;
  const int wm = wid & 1, wn = wid >> 1;
  const int mb = wm * 32;
  const int nb = n0 + wn * 32;

  floatx4 acc00 = {0.f, 0.f, 0.f, 0.f};
  floatx4 acc01 = acc00, acc10 = acc00, acc11 = acc00;

#pragma unroll
  for (int kk = 0; kk < 4; ++kk) {
    int k = kk * 32 + quad * 8;
    short8 a0 = *(const short8*)&Asl[(mb + l15) * 136 + k];
    short8 a1 = *(const short8*)&Asl[(mb + 16 + l15) * 136 + k];
    short8 b0 = *(const short8*)&Bt[(size_t)(nb + l15) * 128 + k];
    short8 b1 = *(const short8*)&Bt[(size_t)(nb + 16 + l15) * 128 + k];
    acc00 = __builtin_amdgcn_mfma_f32_16x16x32_bf16(a0, b0, acc00, 0, 0, 0);
    acc01 = __builtin_amdgcn_mfma_f32_16x16x32_bf16(a0, b1, acc01, 0, 0, 0);
    acc10 = __builtin_amdgcn_mfma_f32_16x16x32_bf16(a1, b0, acc10, 0, 0, 0);
    acc11 = __builtin_amdgcn_mfma_f32_16x16x32_bf16(a1, b1, acc11, 0, 0, 0);
  }

#pragma unroll
  for (int mt = 0; mt < 2; ++mt) {
#pragma unroll
    for (int nt = 0; nt < 2; ++nt) {
      floatx4 acc = (mt == 0) ? (nt == 0 ? acc00 : acc01)
                              : (nt == 0 ? acc10 : acc11);
      int colg = nb + nt * 16 + l15;
      float bv = bias ? bias[colg] : 0.f;
#pragma unroll
      for (int r = 0; r < 4; ++r) {
        int rowg = m0 + mb + mt * 16 + quad * 4 + r;
        if (rowg < M && colg < Nc) {
          float v = acc[r] + bv;
          if (relu) v = fmaxf(v, 0.f);
          Cb2[(size_t)rowg * Nc + colg] = (unsigned short)f2bf(v);
        }
      }
    }
  }
}

// ---------------------------------------------------------------------------
// C[M,128] = act(A_bf16[M,K] @ B + bias), Bt[128][K] bf16, K mult of 64.
// LDS-staged A (proven round-7 version). bf16 output.
// ---------------------------------------------------------------------------
__global__ __launch_bounds__(256) void mm_bf16A(
    const unsigned short* __restrict__ A, const short* __restrict__ Bt,
    const float* __restrict__ bias, unsigned short* __restrict__ Cb2,
    int M, int Nc, int K, int relu)
{
  __shared__ short As[64 * 72];
  const int tid = threadIdx.x;
  const int m0 = blockIdx.x * 64;
  const int n0 = blockIdx.y * 128;
  const int wid = tid >> 6, lane = tid & 63;
  const int l15 = lane & 15, quad = lane >> 4;
  const int wm = wid & 1, wn = wid >> 1;
  const int mb = wm * 32;
  const int nb = n0 + wn * 64;

  floatx4 acc[2][4];
#pragma unroll
  for (int a = 0; a < 2; ++a)
#pragma unroll
    for (int g = 0; g < 4; ++g) acc[a][g] = (floatx4){0.f, 0.f, 0.f, 0.f};

  for (int kb = 0; kb < K; kb += 64) {
    __syncthreads();
#pragma unroll
    for (int it = 0; it < 2; ++it) {
      int idx = tid + it * 256;
      int r = idx >> 3, k8 = (idx & 7) * 8;
      int row = m0 + r; if (row >= M) row = M - 1;
      *(short8*)&As[r * 72 + k8] = *(const short8*)&A[(size_t)row * K + kb + k8];
    }
    __syncthreads();
#pragma unroll
    for (int kk = 0; kk < 2; ++kk) {
      int ko = kk * 32 + quad * 8;
      short8 a0 = *(const short8*)&As[(mb + l15) * 72 + ko];
      short8 a1 = *(const short8*)&As[(mb + 16 + l15) * 72 + ko];
#pragma unroll
      for (int g = 0; g < 4; ++g) {
        int col = nb + g * 16 + l15; if (col >= Nc) col = Nc - 1;
        short8 b = *(const short8*)&Bt[(size_t)col * K + kb + ko];
        acc[0][g] = __builtin_amdgcn_mfma_f32_16x16x32_bf16(a0, b, acc[0][g], 0, 0, 0);
        acc[1][g] = __builtin_amdgcn_mfma_f32_16x16x32_bf16(a1, b, acc[1][g], 0, 0, 0);
      }
    }
  }

#pragma unroll
  for (int mt = 0; mt < 2; ++mt) {
#pragma unroll
    for (int g = 0; g < 4; ++g) {
      int colg = nb + g * 16 + l15;
      if (colg >= Nc) continue;
      float bv = bias[colg];
#pragma unroll
      for (int r = 0; r < 4; ++r) {
        int rowg = m0 + mb + mt * 16 + quad * 4 + r;
        if (rowg < M) {
          float v = acc[mt][g][r] + bv;
          if (relu) v = fmaxf(v, 0.f);
          Cb2[(size_t)rowg * Nc + colg] = (unsigned short)f2bf(v);
        }
      }
    }
  }
}

// ---------------------------------------------------------------------------
// GRU matmul: S[M,512] = [hb | mem_fp32->bf16] @ Bt512^T, K=256. Out bf16.
// ---------------------------------------------------------------------------
__global__ __launch_bounds__(256) void gru_mm(
    const unsigned short* __restrict__ hb, const float* __restrict__ mem,
    const short* __restrict__ Bt512, unsigned short* __restrict__ S, int M)
{
  __shared__ short As[64 * 72];
  const int tid = threadIdx.x;
  const int m0 = blockIdx.x * 64;
  const int n0 = blockIdx.y * 128;
  const int wid = tid >> 6, lane = tid & 63;
  const int l15 = lane & 15, quad = lane >> 4;
  const int wm = wid & 1, wn = wid >> 1;
  const int mb = wm * 32;
  const int nb = n0 + wn * 64;

  floatx4 acc[2][4];
#pragma unroll
  for (int a = 0; a < 2; ++a)
#pragma unroll
    for (int g = 0; g < 4; ++g) acc[a][g] = (floatx4){0.f, 0.f, 0.f, 0.f};

  for (int kb = 0; kb < 256; kb += 64) {
    __syncthreads();
#pragma unroll
    for (int it = 0; it < 2; ++it) {
      int idx = tid + it * 256;
      int r = idx >> 3, k8 = (idx & 7) * 8;
      int row = m0 + r; if (row >= M) row = M - 1;
      if (kb < 128) {
        *(short8*)&As[r * 72 + k8] = *(const short8*)&hb[(size_t)row * 128 + kb + k8];
      } else {
        const float4* m4 = (const float4*)(mem + (size_t)row * 128 + (kb - 128) + k8);
        float4 a = m4[0], b = m4[1];
        short8 p;
        p[0] = f2bf(a.x); p[1] = f2bf(a.y); p[2] = f2bf(a.z); p[3] = f2bf(a.w);
        p[4] = f2bf(b.x); p[5] = f2bf(b.y); p[6] = f2bf(b.z); p[7] = f2bf(b.w);
        *(short8*)&As[r * 72 + k8] = p;
      }
    }
    __syncthreads();
#pragma unroll
    for (int kk = 0; kk < 2; ++kk) {
      int ko = kk * 32 + quad * 8;
      short8 a0 = *(const short8*)&As[(mb + l15) * 72 + ko];
      short8 a1 = *(const short8*)&As[(mb + 16 + l15) * 72 + ko];
#pragma unroll
      for (int g = 0; g < 4; ++g) {
        int col = nb + g * 16 + l15;
        short8 b = *(const short8*)&Bt512[(size_t)col * 256 + kb + ko];
        acc[0][g] = __builtin_amdgcn_mfma_f32_16x16x32_bf16(a0, b, acc[0][g], 0, 0, 0);
        acc[1][g] = __builtin_amdgcn_mfma_f32_16x16x32_bf16(a1, b, acc[1][g], 0, 0, 0);
      }
    }
  }

#pragma unroll
  for (int mt = 0; mt < 2; ++mt) {
#pragma unroll
    for (int g = 0; g < 4; ++g) {
      int colg = nb + g * 16 + l15;
#pragma unroll
      for (int r = 0; r < 4; ++r) {
        int rowg = m0 + mb + mt * 16 + quad * 4 + r;
        if (rowg < M)
          S[(size_t)rowg * 512 + colg] = (unsigned short)f2bf(acc[mt][g][r]);
      }
    }
  }
}

// ---------------------------------------------------------------------------
// Fused GRU gates + global_mean_pool — PARALLEL version: PCHUNK nodes/block
// (grid ~6250 blocks -> full occupancy; run-length + atomic flush unchanged)
// ---------------------------------------------------------------------------
__global__ __launch_bounds__(128) void gru_gate_pool(
    const unsigned short* __restrict__ S, const float* __restrict__ mem,
    const float* __restrict__ bI, const float* __restrict__ bH,
    const int* __restrict__ batch, float* __restrict__ pooled_sums,
    float* __restrict__ cnt, int N)
{
  int n0 = blockIdx.x * PCHUNK;
  int c = threadIdx.x;
  if (n0 >= N) return;
  int end = n0 + PCHUNK; if (end > N) end = N;
  const float bIr = bI[c],       bHr = bH[c];
  const float bIz = bI[128 + c], bHz = bH[128 + c];
  const float bIn = bI[256 + c], bHn = bH[256 + c];
  int cur = batch[n0];
  float acc = 0.f, count = 0.f;
  for (int n = n0; n < end; ++n) {
    int b = batch[n];
    if (b != cur) {
      atomicAdd(&pooled_sums[(size_t)cur * HIDC + c], acc);
      if (c == 0) atomicAdd(&cnt[cur], count);
      acc = 0.f; count = 0.f; cur = b;
    }
    size_t base = (size_t)n * 512;
    float sr  = bf2f(S[base + c])       + bIr + bHr;
    float sz  = bf2f(S[base + 128 + c]) + bIz + bHz;
    float gin = bf2f(S[base + 256 + c]) + bIn;
    float ghn = bf2f(S[base + 384 + c]) + bHn;
    float rg = 1.f / (1.f + __expf(-sr));
    float zg = 1.f / (1.f + __expf(-sz));
    float nc = tanhf(gin + rg * ghn);
    float hv = (1.f - zg) * nc + zg * mem[(size_t)n * 128 + c];
    acc += hv; count += 1.f;
  }
  atomicAdd(&pooled_sums[(size_t)cur * HIDC + c], acc);
  if (c == 0) atomicAdd(&cnt[cur], count);
}

// ---------------------------------------------------------------------------
// alphas from bf16 h: aS/aD[n][h] = h[n,:] . waSD[:,j16]
// ---------------------------------------------------------------------------
__global__ __launch_bounds__(256) void alpha2b_kernel(
    const unsigned short* __restrict__ hb, const float* __restrict__ waSD,
    float* __restrict__ aS, float* __restrict__ aD, int N)
{
  __shared__ float s_wa[2048];
  const int tid = threadIdx.x;
  for (int i = tid; i < 2048; i += 256) s_wa[i] = waSD[i];
  __syncthreads();
  int node = blockIdx.x * 16 + (tid >> 4);
  int j = tid & 15;
  if (node >= N) return;
  const short8* h8 = (const short8*)(hb + (size_t)node * 128);
  float s = 0.f;
#pragma unroll
  for (int k8 = 0; k8 < 16; ++k8) {
    short8 v = h8[k8];
#pragma unroll
    for (int t = 0; t < 8; ++t)
      s += bf2f((unsigned short)v[t]) * s_wa[(k8 * 8 + t) * 16 + j];
  }
  if (j < 8) aS[(size_t)node * 8 + j] = s;
  else       aD[(size_t)node * 8 + (j - 8)] = s;
}

// ---------------------------------------------------------------------------
// CSR build: histogram, 3-stage scan, scatter
// ---------------------------------------------------------------------------
__global__ void hist_kernel(const int* __restrict__ ei, int* __restrict__ deg, int E, int N)
{
  int i = blockIdx.x * 256 + threadIdx.x;
  if (i >= E + N) return;
  int dst = (i < E) ? ei[E + i] : (i - E);
  atomicAdd(&deg[dst], 1);
}

__global__ __launch_bounds__(1024) void scan1_kernel(
    const int* __restrict__ deg, int* __restrict__ rowptr,
    int* __restrict__ bsum, int N)
{
  __shared__ int sd[1024];
  int i = blockIdx.x * 1024 + threadIdx.x;
  int v = (i < N) ? deg[i] : 0;
  sd[threadIdx.x] = v;
  __syncthreads();
  for (int off = 1; off < 1024; off <<= 1) {
    int t = (threadIdx.x >= off) ? sd[threadIdx.x - off] : 0;
    __syncthreads();
    sd[threadIdx.x] += t;
    __syncthreads();
  }
  if (i < N) rowptr[i] = sd[threadIdx.x] - v;
  if (threadIdx.x == 1023) bsum[blockIdx.x] = sd[1023];
}

__global__ __launch_bounds__(64) void scan2_kernel(int* __restrict__ bsum, int nb)
{
  int lane = threadIdx.x;
  int v = (lane < nb) ? bsum[lane] : 0;
  int incl = v;
  for (int off = 1; off < 64; off <<= 1) {
    int t = __shfl_up(incl, off);
    if (lane >= off) incl += t;
  }
  if (lane < nb) bsum[lane] = incl - v;
}

__global__ void scan3_kernel(int* __restrict__ rowptr, const int* __restrict__ bsum,
                             int N, int EN)
{
  int i = blockIdx.x * 256 + threadIdx.x;
  if (i < N) rowptr[i] += bsum[i >> 10];
  if (i == 0) rowptr[N] = EN;
}

__global__ void scatter_kernel(const int* __restrict__ ei, const int* __restrict__ rowptr,
                               int* __restrict__ cursor, int* __restrict__ csr_src,
                               int E, int N)
{
  int i = blockIdx.x * 256 + threadIdx.x;
  if (i >= E + N) return;
  int src, dst;
  if (i < E) { src = ei[i]; dst = ei[E + i]; }
  else { src = i - E; dst = i - E; }
  int pos = rowptr[dst] + atomicAdd(&cursor[dst], 1);
  csr_src[pos] = src;
}

// ---------------------------------------------------------------------------
// GAT aggregation v5 (proven): one wave per dst, <=64 VGPR, wave-private
// LDS p/src staging, 8 outstanding gathers, no barriers.
// ---------------------------------------------------------------------------
__global__ __launch_bounds__(256, 8) void gat_agg5(
    const unsigned short* __restrict__ hb, const int* __restrict__ rowptr,
    const int* __restrict__ csr_src, const float* __restrict__ aS,
    const float* __restrict__ aD, unsigned short* __restrict__ agg, int N)
{
  __shared__ float s_p[4][48][8];   // per-wave p (unnormalized), 0 for padding
  __shared__ int   s_src[4][48];    // per-wave src ids, 0 for padding
  const int wid = threadIdx.x >> 6;
  const int lane = threadIdx.x & 63;
  const int dst = blockIdx.x * 4 + wid;
  if (dst >= N) return;
  const int el = lane >> 3, hh = lane & 7;
  const int start = rowptr[dst];
  const int deg = rowptr[dst + 1] - start;
  const float adh = aD[(size_t)dst * 8 + hh];

  // pass 1: scores (src ids staged straight to LDS), per-head max
  float v_c[MAXI];
  float m = -1e30f;
#pragma unroll
  for (int i = 0; i < MAXI; ++i) {
    int e = i * 8 + el;
    int s = 0; float v = -1e30f;
    if (e < deg) {
      s = csr_src[start + e];
      v = aS[(size_t)s * 8 + hh] + adh;
      v = (v > 0.f) ? v : 0.2f * v;
    }
    if (hh == 0) s_src[wid][e] = s;
    v_c[i] = v;
    m = fmaxf(m, v);
  }
  for (int e0 = MAXI * 8; e0 < deg; e0 += 8) {
    int e = e0 + el;
    if (e < deg) {
      int s = csr_src[start + e];
      float v = aS[(size_t)s * 8 + hh] + adh;
      v = (v > 0.f) ? v : 0.2f * v;
      m = fmaxf(m, v);
    }
  }
  m = fmaxf(m, __shfl_xor(m, 8));
  m = fmaxf(m, __shfl_xor(m, 16));
  m = fmaxf(m, __shfl_xor(m, 32));

  // p + stage to wave-private LDS
  float dsum = 0.f;
#pragma unroll
  for (int i = 0; i < MAXI; ++i) {
    int e = i * 8 + el;
    float p = (e < deg && v_c[i] > -1e29f) ? __expf(v_c[i] - m) : 0.f;
    dsum += p;
    s_p[wid][e][hh] = p;
  }

  // pass 2: batched gather + FMA (p=0 padding, src=0 padding -> branch-free)
  float accx[8], accy[8];
#pragma unroll
  for (int q = 0; q < 8; ++q) { accx[q] = 0.f; accy[q] = 0.f; }
  const unsigned* hb32 = (const unsigned*)hb;
  const int ng = (deg < MAXI * 8) ? ((deg + 7) >> 3) : MAXI;

  for (int i = 0; i < ng; ++i) {
    int4 sa = *(const int4*)&s_src[wid][i * 8];
    int4 sb = *(const int4*)&s_src[wid][i * 8 + 4];
    unsigned hv[8];
    hv[0] = hb32[(unsigned)sa.x * 64 + lane];
    hv[1] = hb32[(unsigned)sa.y * 64 + lane];
    hv[2] = hb32[(unsigned)sa.z * 64 + lane];
    hv[3] = hb32[(unsigned)sa.w * 64 + lane];
    hv[4] = hb32[(unsigned)sb.x * 64 + lane];
    hv[5] = hb32[(unsigned)sb.y * 64 + lane];
    hv[6] = hb32[(unsigned)sb.z * 64 + lane];
    hv[7] = hb32[(unsigned)sb.w * 64 + lane];
#pragma unroll
    for (int ee = 0; ee < 8; ++ee) {
      float4 pA = *(const float4*)&s_p[wid][i * 8 + ee][0];
      float4 pB = *(const float4*)&s_p[wid][i * 8 + ee][4];
      float hx = bf2f((unsigned short)hv[ee]);
      float hy = bf2f((unsigned short)(hv[ee] >> 16));
      accx[0] = fmaf(pA.x, hx, accx[0]); accy[0] = fmaf(pA.x, hy, accy[0]);
      accx[1] = fmaf(pA.y, hx, accx[1]); accy[1] = fmaf(pA.y, hy, accy[1]);
      accx[2] = fmaf(pA.z, hx, accx[2]); accy[2] = fmaf(pA.z, hy, accy[2]);
      accx[3] = fmaf(pA.w, hx, accx[3]); accy[3] = fmaf(pA.w, hy, accy[3]);
      accx[4] = fmaf(pB.x, hx, accx[4]); accy[4] = fmaf(pB.x, hy, accy[4]);
      accx[5] = fmaf(pB.y, hx, accx[5]); accy[5] = fmaf(pB.y, hy, accy[5]);
      accx[6] = fmaf(pB.z, hx, accx[6]); accy[6] = fmaf(pB.z, hy, accy[6]);
      accx[7] = fmaf(pB.w, hx, accx[7]); accy[7] = fmaf(pB.w, hy, accy[7]);
    }
  }
  // overflow path (deg > 48): recompute + shuffle broadcast
  const int c2 = lane * 2;
  for (int e0 = MAXI * 8; e0 < deg; e0 += 8) {
    int e = e0 + el;
    float p = 0.f; int s = 0;
    if (e < deg) {
      s = csr_src[start + e];
      float v = aS[(size_t)s * 8 + hh] + adh;
      v = (v > 0.f) ? v : 0.2f * v;
      p = __expf(v - m);
    }
    dsum += p;
    int cnt = deg - e0; if (cnt > 8) cnt = 8;
    for (int ee = 0; ee < cnt; ++ee) {
      int se = __shfl(s, ee * 8);
      unsigned hv = *(const unsigned*)&hb[(size_t)se * 128 + c2];
      float hx = bf2f((unsigned short)hv);
      float hy = bf2f((unsigned short)(hv >> 16));
#pragma unroll
      for (int q = 0; q < 8; ++q) {
        float pq = __shfl(p, ee * 8 + q);
        accx[q] = fmaf(pq, hx, accx[q]);
        accy[q] = fmaf(pq, hy, accy[q]);
      }
    }
  }

  dsum += __shfl_xor(dsum, 8);
  dsum += __shfl_xor(dsum, 16);
  dsum += __shfl_xor(dsum, 32);
  float inv = 1.f / (dsum + 1e-16f);

#pragma unroll
  for (int q = 0; q < 8; ++q) {
    float invq = __shfl(inv, q);                  // lane q holds hh=q denom
    float ax = accx[q] * invq, ay = accy[q] * invq;
    unsigned pk = ((unsigned)(unsigned short)f2bf(ay) << 16) |
                  (unsigned)(unsigned short)f2bf(ax);
    *(unsigned*)&agg[(size_t)dst * 1024 + q * 128 + c2] = pk;
  }
}

// ---------------------------------------------------------------------------
// finalize pooled, classifier MLP, softmax
// ---------------------------------------------------------------------------
__global__ __launch_bounds__(64) void classifier_kernel(
    float* __restrict__ pooled, const float* __restrict__ cnt,
    const float* __restrict__ c1W, const float* __restrict__ c1b,
    const float* __restrict__ c2W, const float* __restrict__ c2b,
    float* __restrict__ logits, float* __restrict__ preds)
{
  int g = blockIdx.x, j = threadIdx.x;
  __shared__ float sp[128];
  __shared__ float hid[64];
  __shared__ float lg[3];
  float invc = 1.f / fmaxf(cnt[g], 1.f);
  float p0 = pooled[(size_t)g * 128 + j] * invc;
  float p1 = pooled[(size_t)g * 128 + 64 + j] * invc;
  pooled[(size_t)g * 128 + j] = p0;
  pooled[(size_t)g * 128 + 64 + j] = p1;
  sp[j] = p0; sp[j + 64] = p1;
  __syncthreads();
  float a = c1b[j];
#pragma unroll
  for (int k = 0; k < 128; ++k) a = fmaf(sp[k], c1W[k * 64 + j], a);
  hid[j] = fmaxf(a, 0.f);
  __syncthreads();
  if (j < NCLS) {
    float t = c2b[j];
#pragma unroll
    for (int k = 0; k < 64; ++k) t = fmaf(hid[k], c2W[k * NCLS + j], t);
    logits[(size_t)g * NCLS + j] = t;
    lg[j] = t;
  }
  __syncthreads();
  if (j < NCLS) {
    float mx = fmaxf(lg[0], fmaxf(lg[1], lg[2]));
    float e0 = __expf(lg[0] - mx), e1 = __expf(lg[1] - mx), e2 = __expf(lg[2] - mx);
    float mine = (j == 0) ? e0 : ((j == 1) ? e1 : e2);
    preds[(size_t)g * NCLS + j] = mine / (e0 + e1 + e2);
  }
}

// ---------------------------------------------------------------------------
extern "C" void kernel_launch(void* const* d_in, const int* in_sizes, int n_in,
                              void* d_out, int out_size, void* d_ws, size_t ws_size,
                              hipStream_t stream)
{
  const float* x       = (const float*)d_in[0];
  const int*   ei      = (const int*)d_in[1];
  const int*   batch   = (const int*)d_in[2];
  const float* memory  = (const float*)d_in[3];
  const float* enc_W   = (const float*)d_in[4];
  const float* enc_b   = (const float*)d_in[5];
  const float* gat_W   = (const float*)d_in[6];   // [NL,128,1024]
  const float* att_src = (const float*)d_in[7];
  const float* att_dst = (const float*)d_in[8];
  const float* gat_b   = (const float*)d_in[9];
  const float* W_ih    = (const float*)d_in[10];
  const float* W_hh    = (const float*)d_in[11];
  const float* b_ih    = (const float*)d_in[12];
  const float* b_hh    = (const float*)d_in[13];
  const float* c1W     = (const float*)d_in[14];
  const float* c1b     = (const float*)d_in[15];
  const float* c2W     = (const float*)d_in[16];
  const float* c2b     = (const float*)d_in[17];

  const int N = in_sizes[0] / HIDC;
  const int E = in_sizes[1] / 2;
  const int EN = E + N;
  const int NB = (N + 1023) / 1024;

  char* ws = (char*)d_ws;
  size_t off = 0;
  auto alloc = [&](size_t bytes) -> void* {
    void* p = ws + off;
    off += (bytes + 255) & ~(size_t)255;
    return p;
  };
  unsigned short* hb0 = (unsigned short*)alloc((size_t)N * HIDC * 2);
  unsigned short* hb1 = (unsigned short*)alloc((size_t)N * HIDC * 2);
  unsigned short* agg = (unsigned short*)alloc((size_t)N * 1024 * 2);  // also S[N,512]
  float* aS     = (float*)alloc((size_t)N * NHEAD * 4);
  float* aD     = (float*)alloc((size_t)N * NHEAD * 4);
  short* encT   = (short*)alloc((size_t)128 * 128 * 2);
  short* Wp     = (short*)alloc((size_t)NLAY * 131072 * 2);
  float* waSD   = (float*)alloc((size_t)NLAY * 2048 * 4);
  short* Bt512  = (short*)alloc((size_t)512 * 256 * 2);
  int*   rowptr = (int*)alloc((size_t)(N + 1) * 4);
  // cursor + degtmp adjacent -> single memset
  size_t zoff0 = off;
  int*   cursor = (int*)alloc((size_t)N * 4);
  int*   degtmp = (int*)alloc((size_t)N * 4);
  size_t zbytes = off - zoff0;
  int*   bsum   = (int*)alloc(64 * 4);
  int*   csr    = (int*)alloc((size_t)EN * 4);
  float* cntbuf = (float*)alloc(64 * 4);

  float* out_logits = (float*)d_out;
  float* out_pooled = (float*)d_out + NGRAPH * NCLS;
  float* out_preds  = (float*)d_out + NGRAPH * NCLS + NGRAPH * HIDC;

  hipMemsetAsync(d_out, 0, (size_t)out_size * 4, stream);
  hipMemsetAsync(cntbuf, 0, 64 * 4, stream);
  hipMemsetAsync(cursor, 0, zbytes, stream);

  // CSR build
  hist_kernel<<<(EN + 255) / 256, 256, 0, stream>>>(ei, degtmp, E, N);
  scan1_kernel<<<NB, 1024, 0, stream>>>(degtmp, rowptr, bsum, N);
  scan2_kernel<<<1, 64, 0, stream>>>(bsum, NB);
  scan3_kernel<<<(N + 255) / 256, 256, 0, stream>>>(rowptr, bsum, N, EN);
  scatter_kernel<<<(EN + 255) / 256, 256, 0, stream>>>(ei, rowptr, cursor, csr, E, N);

  // weight prep
  convt_kernel<<<(128 * 128 + 255) / 256, 256, 0, stream>>>(enc_W, encT, 128, 128);
  rearr_kernel<<<(NLAY * 131072 + 255) / 256, 256, 0, stream>>>(gat_W, Wp);
  {
    dim3 g(NLAY, 8);
    wa_kernel<<<g, 256, 0, stream>>>(gat_W, att_src, att_dst, waSD);
  }
  build_gru_B<<<(512 * 256 + 255) / 256, 256, 0, stream>>>(W_ih, W_hh, Bt512);

  // encoder: hb0 = bf16(relu(x @ enc_W + enc_b))
  {
    dim3 g((N + 63) / 64, 2);
    mm_bf16<<<g, 256, 0, stream>>>(x, encT, enc_b, hb0, N, HIDC, 1);
  }

  unsigned short* hbcur = hb0;
  unsigned short* hbnxt = hb1;
  for (int l = 0; l < NLAY; ++l) {
    alpha2b_kernel<<<(N + 15) / 16, 256, 0, stream>>>(
        hbcur, waSD + (size_t)l * 2048, aS, aD, N);
    gat_agg5<<<(N + 3) / 4, 256, 0, stream>>>(hbcur, rowptr, csr, aS, aD, agg, N);
    dim3 g((N + 63) / 64, 1);
    mm_bf16A<<<g, 256, 0, stream>>>(agg, Wp + (size_t)l * 131072,
                                    gat_b + (size_t)l * HIDC, hbnxt,
                                    N, HIDC, 1024, (l < NLAY - 1) ? 1 : 0);
    unsigned short* tb = hbcur; hbcur = hbnxt; hbnxt = tb;
  }

  // fused-weight GRU: S = [hb|mem] @ Bt512^T (bf16), then gates+pool fused
  {
    dim3 g((N + 63) / 64, 4);
    gru_mm<<<g, 256, 0, stream>>>(hbcur, memory, Bt512, agg, N);   // agg reused as S
  }
  gru_gate_pool<<<(N + PCHUNK - 1) / PCHUNK, 128, 0, stream>>>(
      agg, memory, b_ih, b_hh, batch, out_pooled, cntbuf, N);

  classifier_kernel<<<NGRAPH, 64, 0, stream>>>(out_pooled, cntbuf, c1W, c1b, c2W, c2b,
                                               out_logits, out_preds);
}